// Round 2
// baseline (408.037 us; speedup 1.0000x reference)
//
#include <hip/hip_runtime.h>
#include <hip/hip_bf16.h>

// SocialGNN: 2-layer GCN, N=100000 nodes, E=1600000 edges (+ self loops),
// feat 256 -> 128 (relu) -> 16.
//
// R11: agg1 = R10's XCD-L2-resident feature-chunked gather (confirmed: FETCH
// 188->77 MB) + two fixes for the R10 regression (64->85us):
//  (a) degree-sorted node permutation (counting sort, 64 bins) so the 16
//      nodes of a wave have equal degree -- kills the max-of-16 divergence
//      (~1.7x issue inflation measured by the R10 model);
//  (b) coalesced csr loads: lane q loads csr[e+q] (contiguous 16B per group)
//      and __shfl-broadcasts within the 4-lane group -- index TA cost 21->5us.
// History: R2 -- never funnel E atomics into <1K addresses. R4 -- bf16
// intermediates halve gather traffic. R5/R8 -- agg1 2 nodes/wave. R7 --
// per-wave-redundant MFMA operand streams from global = 2x regression.
// R9 -- resident-B LDS gemm1. R10 -- XCD chunking cuts HBM 2.4x but 16
// nodes/wave divergence + 2 L1-lines/edge request tax = net regression.

typedef __attribute__((ext_vector_type(8))) short short8;
typedef __attribute__((ext_vector_type(4))) float f32x4;

__device__ inline unsigned short f2bf(float f) {
    __hip_bfloat16 h = __float2bfloat16(f);
    return *(unsigned short*)&h;
}
__device__ inline float bf2f(unsigned short u) {
    unsigned int v = ((unsigned int)u) << 16;
    return *(float*)&v;
}

#define N_FEAT_IN 256
#define NBUCK 1024     // dst>>7; used buckets = ceil(n/128) = 782
#define NBINBLK 256    // partition blocks; bbc is [NBUCK][NBINBLK]
#define NDBIN 64       // degree-sort bins (deg clamped to 63)
#define DBLK 512       // max blocks for degree sort (n <= 131072)

// ---------------- partition pass 1: per-(block,bucket) LDS histogram ----------------
__global__ __launch_bounds__(256) void k_bhist(const int* __restrict__ dst,
                                               int* __restrict__ bbc, int E, int chunk) {
    __shared__ int lcnt[NBUCK];
    for (int i = threadIdx.x; i < NBUCK; i += 256) lcnt[i] = 0;
    __syncthreads();
    int start = blockIdx.x * chunk;
    int end = min(start + chunk, E);
    for (int e = start + threadIdx.x; e < end; e += 256)
        atomicAdd(&lcnt[dst[e] >> 7], 1);
    __syncthreads();
    for (int i = threadIdx.x; i < NBUCK; i += 256)
        bbc[i * NBINBLK + blockIdx.x] = lcnt[i];
}

// ---- partition pass 2: per-bucket local exclusive scan across blocks + totals ----
__global__ __launch_bounds__(256) void k_bexscan(int* __restrict__ bbc,
                                                 int* __restrict__ btot) {
    __shared__ int ts[NBINBLK];
    int bucket = blockIdx.x;
    int t = threadIdx.x;
    int v = bbc[bucket * NBINBLK + t];
    ts[t] = v; __syncthreads();
    for (int off = 1; off < NBINBLK; off <<= 1) {
        int x = (t >= off) ? ts[t - off] : 0;
        __syncthreads();
        ts[t] += x;
        __syncthreads();
    }
    bbc[bucket * NBINBLK + t] = ts[t] - v;   // local exclusive (no base yet)
    if (t == NBINBLK - 1) btot[bucket] = ts[t];
}

// ---------------- bucket-total exclusive scan -> bucket bases ----------------
__global__ __launch_bounds__(1024) void k_bscan(const int* __restrict__ btot,
                                                int* __restrict__ bbase) {
    __shared__ int ts[NBUCK];
    int t = threadIdx.x;
    int v = btot[t];
    ts[t] = v; __syncthreads();
    for (int off = 1; off < NBUCK; off <<= 1) {
        int x = (t >= off) ? ts[t - off] : 0;
        __syncthreads();
        ts[t] += x;
        __syncthreads();
    }
    bbase[t] = ts[t] - v;  // exclusive
}

// ---------------- partition pass 3: binned write (24-bit packed) ----------------
// packed edge: bits 0-16 src (n<2^17), bits 17-23 dst&127.
__global__ __launch_bounds__(256) void k_bin2(const int* __restrict__ src,
                                              const int* __restrict__ dst,
                                              const int* __restrict__ bbc,
                                              const int* __restrict__ bbase,
                                              int* __restrict__ ebuf, int E, int chunk) {
    __shared__ int lcur[NBUCK];
    for (int i = threadIdx.x; i < NBUCK; i += 256)
        lcur[i] = bbc[i * NBINBLK + blockIdx.x] + bbase[i];
    __syncthreads();
    int start = blockIdx.x * chunk;
    int end = min(start + chunk, E);
    for (int e = start + threadIdx.x; e < end; e += 256) {
        int s = src[e], d = dst[e];
        int pos = atomicAdd(&lcur[d >> 7], 1);  // LDS atomic
        ebuf[pos] = s | ((d & 127) << 17);
    }
}

// ---- per-bucket counting sort: ebuf window -> csr; also row_ptr, dinv ----
__global__ __launch_bounds__(256) void k_sortb(const int* __restrict__ ebuf,
                                               const int* __restrict__ bbase,
                                               int* __restrict__ row_ptr,
                                               float* __restrict__ dinv,
                                               int* __restrict__ csr, int n, int E) {
    __shared__ int lcnt[128];
    __shared__ int lcur[128];
    int b = blockIdx.x;
    int node0 = b << 7;
    int nodes = min(128, n - node0);
    int t = threadIdx.x;
    int s_start = bbase[b];
    int s_end = bbase[b + 1];
    if (t < 128) lcnt[t] = 0;
    __syncthreads();
    for (int e = s_start + t; e < s_end; e += 256)
        atomicAdd(&lcnt[(ebuf[e] >> 17) & 127], 1);
    __syncthreads();
    int deg = (t < 128) ? lcnt[t] : 0;
    if (t < 128) lcur[t] = deg;
    __syncthreads();
    for (int off = 1; off < 128; off <<= 1) {
        int x = 0;
        if (t < 128 && t >= off) x = lcur[t - off];
        __syncthreads();
        if (t < 128) lcur[t] += x;
        __syncthreads();
    }
    if (t < 128) {
        int excl = s_start + lcur[t] - deg;
        if (t < nodes) {
            row_ptr[node0 + t] = excl;
            dinv[node0 + t] = rsqrtf((float)deg + 1.0f);  // +1 self-loop
        }
        lcur[t] = excl;  // write cursor
    }
    if (b == 0 && t == 0) row_ptr[n] = E;
    __syncthreads();
    for (int e = s_start + t; e < s_end; e += 256) {
        int p = ebuf[e];
        int pos = atomicAdd(&lcur[(p >> 17) & 127], 1);  // LDS atomic
        csr[pos] = p & 0x1FFFF;
    }
}

// ---------------- degree sort: counting sort of nodes by min(deg,63) ----------------
__global__ __launch_bounds__(256) void k_dh(const int* __restrict__ rp,
                                            int* __restrict__ dcnt, int n) {
    __shared__ int h[NDBIN];
    if (threadIdx.x < NDBIN) h[threadIdx.x] = 0;
    __syncthreads();
    int node = blockIdx.x * 256 + threadIdx.x;
    if (node < n) {
        int deg = rp[node + 1] - rp[node];
        atomicAdd(&h[min(deg, NDBIN - 1)], 1);
    }
    __syncthreads();
    if (threadIdx.x < NDBIN) dcnt[threadIdx.x * DBLK + blockIdx.x] = h[threadIdx.x];
}

__global__ __launch_bounds__(512) void k_dscan(int* __restrict__ dcnt,
                                               int* __restrict__ dtot, int nblk) {
    __shared__ int ts[DBLK];
    int b = blockIdx.x;  // bin
    int t = threadIdx.x;
    int v = (t < nblk) ? dcnt[b * DBLK + t] : 0;
    ts[t] = v; __syncthreads();
    for (int off = 1; off < DBLK; off <<= 1) {
        int x = (t >= off) ? ts[t - off] : 0;
        __syncthreads();
        ts[t] += x;
        __syncthreads();
    }
    if (t < nblk) dcnt[b * DBLK + t] = ts[t] - v;  // local exclusive
    if (t == DBLK - 1) dtot[b] = ts[t];
}

__global__ void k_dbase(const int* __restrict__ dtot, int* __restrict__ dbase) {
    __shared__ int ts[NDBIN];
    int t = threadIdx.x;  // 64 threads
    int v = dtot[t];
    ts[t] = v; __syncthreads();
    for (int off = 1; off < NDBIN; off <<= 1) {
        int x = (t >= off) ? ts[t - off] : 0;
        __syncthreads();
        ts[t] += x;
        __syncthreads();
    }
    dbase[t] = ts[t] - v;
}

__global__ __launch_bounds__(256) void k_dscat(const int* __restrict__ rp,
                                               const int* __restrict__ dcnt,
                                               const int* __restrict__ dbase,
                                               int* __restrict__ perm, int n) {
    __shared__ int lcur[NDBIN];
    if (threadIdx.x < NDBIN)
        lcur[threadIdx.x] = dcnt[threadIdx.x * DBLK + blockIdx.x] + dbase[threadIdx.x];
    __syncthreads();
    int node = blockIdx.x * 256 + threadIdx.x;
    if (node < n) {
        int deg = rp[node + 1] - rp[node];
        int pos = atomicAdd(&lcur[min(deg, NDBIN - 1)], 1);  // LDS atomic
        perm[pos] = node;
    }
}

// ------ W1 [256][128] f32 -> W1t packed [kq 0..31][n 0..127][j 0..7] bf16 ------
__global__ void k_prep(const float* __restrict__ W1, unsigned short* __restrict__ W1t) {
    int nn = blockIdx.x;          // 0..127
    int k = threadIdx.x;          // 0..255
    int kq = k >> 3, j = k & 7;
    W1t[kq * 1024 + nn * 8 + j] = f2bf(W1[k * 128 + nn]);
}

// ---- zero the 8 dummy rows (index n) of chunk-major h1s [8][n+1][16] ----
__global__ void k_zpad(unsigned short* __restrict__ h1s, int n) {
    int t = threadIdx.x;          // 128 threads
    int c = t >> 4, j = t & 15;
    h1s[((size_t)c * (n + 1) + n) * 16 + j] = 0;
}

// ---------------- GEMM1 (MFMA, resident-B): X[M,256]f32 @ W1 -> h1s bf16, *dinv -----
// W1 (64 KB bf16, kq-major) in LDS once; barrier-free k-loop. Epilogue stores
// CHUNK-MAJOR h1s [8][M+1][16] (chunk = col>>4) for agg1; row M is dummy-zero.
__global__ __launch_bounds__(256) void k_gemm1(const float* __restrict__ X,
                                               const unsigned short* __restrict__ W1t,
                                               const float* __restrict__ dinv,
                                               unsigned short* __restrict__ h1s, int M) {
    __shared__ unsigned short Bs[32768];   // 64 KB, [kq][n][8]
    const int tid = threadIdx.x;
    const int wv = tid >> 6;
    const int lane = tid & 63;
    const int hq = lane >> 4;       // quad 0..3
    const int l15 = lane & 15;
    const int block_row = blockIdx.x * 64;

#pragma unroll
    for (int i = 0; i < 16; ++i)
        ((uint4*)Bs)[tid + i * 256] = ((const uint4*)W1t)[tid + i * 256];
    __syncthreads();

    int arow = block_row + wv * 16 + l15;
    if (arow >= M) arow = M - 1;                       // clamp; stores masked
    const float* xp = X + (size_t)arow * 256 + hq * 8;

    f32x4 acc[8];
#pragma unroll
    for (int c = 0; c < 8; ++c) acc[c] = (f32x4){0.f, 0.f, 0.f, 0.f};

#pragma unroll
    for (int ks = 0; ks < 8; ++ks) {                   // k0 = 32*ks
        float4 a0 = *(const float4*)(xp + 32 * ks);
        float4 a1 = *(const float4*)(xp + 32 * ks + 4);
        short8 a;
        a[0] = (short)f2bf(a0.x); a[1] = (short)f2bf(a0.y);
        a[2] = (short)f2bf(a0.z); a[3] = (short)f2bf(a0.w);
        a[4] = (short)f2bf(a1.x); a[5] = (short)f2bf(a1.y);
        a[6] = (short)f2bf(a1.z); a[7] = (short)f2bf(a1.w);
        const unsigned short* bp = Bs + (ks * 4 + hq) * 1024 + l15 * 8;
#pragma unroll
        for (int c = 0; c < 8; ++c) {
            short8 b = *(const short8*)(bp + c * 128);
            acc[c] = __builtin_amdgcn_mfma_f32_16x16x32_bf16(a, b, acc[c], 0, 0, 0);
        }
    }
    // D: row = 16wv + hq*4 + r, col = c*16 + l15 -> chunk-major store
    const size_t CSTRIDE = (size_t)(M + 1) * 16;
#pragma unroll
    for (int r = 0; r < 4; ++r) {
        int row = block_row + 16 * wv + hq * 4 + r;
        if (row < M) {
            float dv = dinv[row];
#pragma unroll
            for (int c = 0; c < 8; ++c) {
                h1s[(size_t)c * CSTRIDE + (size_t)row * 16 + l15] = f2bf(acc[c][r] * dv);
            }
        }
    }
}

// ---------------- agg1 (R11): chunked gather, degree-sorted, coalesced idx ----------
// h1s chunk-major [8][n+1][16] bf16 (row n = zeros); tbuf chunk-major [8][n][16].
// chunk c = blockIdx&7 -> XCD c; 3.2 MB slice L2-resident. 4 lanes/node, uint2
// per lane. Wave's 16 nodes are perm-adjacent => equal degree (no divergence).
// Indices: lane q loads csr[e+q] (coalesced 16B/group), __shfl-broadcast in
// group; next step's indices prefetched.
__global__ __launch_bounds__(256) void k_agg1(const unsigned short* __restrict__ h1s,
                                              const int* __restrict__ rp,
                                              const int* __restrict__ csr,
                                              const int* __restrict__ perm,
                                              const float* __restrict__ dinv,
                                              const float* __restrict__ b1,
                                              unsigned short* __restrict__ tbuf, int n) {
    const int c = blockIdx.x & 7;            // feature chunk == XCD id
    const int nb = blockIdx.x >> 3;
    const int idx = nb * 64 + (threadIdx.x >> 2);
    const int lane = threadIdx.x & 63;
    const int q = threadIdx.x & 3;           // lane within 4-lane node group
    const int gbase = lane & ~3;             // group's base lane in wave
    if (idx >= n) return;
    const int node = perm[idx];
    const uint2* hv = (const uint2*)(h1s + (size_t)c * (n + 1) * 16);  // [n+1][4] uint2
    uint2 us = hv[(size_t)node * 4 + q];     // self (already *dinv)
    float a0 = bf2f((unsigned short)(us.x & 0xffff));
    float a1 = bf2f((unsigned short)(us.x >> 16));
    float a2 = bf2f((unsigned short)(us.y & 0xffff));
    float a3 = bf2f((unsigned short)(us.y >> 16));
    int e = rp[node];
    const int end = rp[node + 1];
    const int efull = e + ((end - e) & ~3);
    int myidx = (e < efull) ? csr[e + q] : 0;
    while (e < efull) {
        int i0 = __shfl(myidx, gbase + 0);
        int i1 = __shfl(myidx, gbase + 1);
        int i2 = __shfl(myidx, gbase + 2);
        int i3 = __shfl(myidx, gbase + 3);
        e += 4;
        int nidx = (e < efull) ? csr[e + q] : 0;   // prefetch next quad
        uint2 u0 = hv[(size_t)i0 * 4 + q];
        uint2 u1 = hv[(size_t)i1 * 4 + q];
        uint2 u2 = hv[(size_t)i2 * 4 + q];
        uint2 u3 = hv[(size_t)i3 * 4 + q];
        a0 += (bf2f((unsigned short)(u0.x & 0xffff)) + bf2f((unsigned short)(u1.x & 0xffff))) +
              (bf2f((unsigned short)(u2.x & 0xffff)) + bf2f((unsigned short)(u3.x & 0xffff)));
        a1 += (bf2f((unsigned short)(u0.x >> 16)) + bf2f((unsigned short)(u1.x >> 16))) +
              (bf2f((unsigned short)(u2.x >> 16)) + bf2f((unsigned short)(u3.x >> 16)));
        a2 += (bf2f((unsigned short)(u0.y & 0xffff)) + bf2f((unsigned short)(u1.y & 0xffff))) +
              (bf2f((unsigned short)(u2.y & 0xffff)) + bf2f((unsigned short)(u3.y & 0xffff)));
        a3 += (bf2f((unsigned short)(u0.y >> 16)) + bf2f((unsigned short)(u1.y >> 16))) +
              (bf2f((unsigned short)(u2.y >> 16)) + bf2f((unsigned short)(u3.y >> 16)));
        myidx = nidx;
    }
    for (; e < end; ++e) {
        uint2 u = hv[(size_t)csr[e] * 4 + q];
        a0 += bf2f((unsigned short)(u.x & 0xffff));
        a1 += bf2f((unsigned short)(u.x >> 16));
        a2 += bf2f((unsigned short)(u.y & 0xffff));
        a3 += bf2f((unsigned short)(u.y >> 16));
    }
    float dv = dinv[node];
    float4 bb = *(const float4*)(b1 + c * 16 + q * 4);
    float t0 = fmaxf(dv * a0 + bb.x, 0.0f);
    float t1 = fmaxf(dv * a1 + bb.y, 0.0f);
    float t2 = fmaxf(dv * a2 + bb.z, 0.0f);
    float t3 = fmaxf(dv * a3 + bb.w, 0.0f);
    uint2 packed;
    packed.x = (unsigned int)f2bf(t0) | ((unsigned int)f2bf(t1) << 16);
    packed.y = (unsigned int)f2bf(t2) | ((unsigned int)f2bf(t3) << 16);
    ((uint2*)tbuf)[(size_t)c * n * 4 + (size_t)node * 4 + q] = packed;
}

// ---------------- GEMM2: tbuf (chunk-major [8][n][16] bf16) @ W2 -> h2s, *dinv -------
__global__ __launch_bounds__(256) void k_gemm2(const unsigned short* __restrict__ tbuf,
                                               const float* __restrict__ W2,
                                               const float* __restrict__ dinv,
                                               unsigned short* __restrict__ h2s, int n) {
    __shared__ float w2s[128 * 16];
    for (int i = threadIdx.x; i < 2048; i += 256) w2s[i] = W2[i];
    __syncthreads();
    int gid = blockIdx.x * 256 + threadIdx.x;
    int node = gid >> 4;
    int o = gid & 15;
    if (node >= n) return;
    const uint4* tv = (const uint4*)tbuf;    // chunk slice: node -> 2 uint4 (32 B)
    float acc = 0.0f;
#pragma unroll
    for (int cc = 0; cc < 8; ++cc) {
        size_t base = ((size_t)cc * n + node) * 2;
        uint4 u0 = tv[base];
        uint4 u1 = tv[base + 1];
        int k = cc * 16;
        acc += __uint_as_float(u0.x << 16) * w2s[(k + 0) * 16 + o];
        acc += __uint_as_float(u0.x & 0xffff0000u) * w2s[(k + 1) * 16 + o];
        acc += __uint_as_float(u0.y << 16) * w2s[(k + 2) * 16 + o];
        acc += __uint_as_float(u0.y & 0xffff0000u) * w2s[(k + 3) * 16 + o];
        acc += __uint_as_float(u0.z << 16) * w2s[(k + 4) * 16 + o];
        acc += __uint_as_float(u0.z & 0xffff0000u) * w2s[(k + 5) * 16 + o];
        acc += __uint_as_float(u0.w << 16) * w2s[(k + 6) * 16 + o];
        acc += __uint_as_float(u0.w & 0xffff0000u) * w2s[(k + 7) * 16 + o];
        acc += __uint_as_float(u1.x << 16) * w2s[(k + 8) * 16 + o];
        acc += __uint_as_float(u1.x & 0xffff0000u) * w2s[(k + 9) * 16 + o];
        acc += __uint_as_float(u1.y << 16) * w2s[(k + 10) * 16 + o];
        acc += __uint_as_float(u1.y & 0xffff0000u) * w2s[(k + 11) * 16 + o];
        acc += __uint_as_float(u1.z << 16) * w2s[(k + 12) * 16 + o];
        acc += __uint_as_float(u1.z & 0xffff0000u) * w2s[(k + 13) * 16 + o];
        acc += __uint_as_float(u1.w << 16) * w2s[(k + 14) * 16 + o];
        acc += __uint_as_float(u1.w & 0xffff0000u) * w2s[(k + 15) * 16 + o];
    }
    h2s[(size_t)node * 16 + o] = f2bf(acc * dinv[node]);
}

// ---------------- agg2: 4 lanes/node, uint2 (4 bf16 feats) per lane ----------------
__global__ __launch_bounds__(256) void k_agg2(const unsigned short* __restrict__ h2s,
                                              const int* __restrict__ rp,
                                              const int* __restrict__ csr,
                                              const float* __restrict__ dinv,
                                              const float* __restrict__ b2,
                                              float* __restrict__ out, int n) {
    int wid = (blockIdx.x * 256 + threadIdx.x) >> 6;
    int lane = threadIdx.x & 63;
    int slot = lane >> 2;
    int q = lane & 3;
    int node = wid * 16 + slot;
    bool valid = node < n;
    int nodec = valid ? node : n - 1;
    int start = rp[nodec];
    int deg = rp[nodec + 1] - start;
    int mx = deg;
#pragma unroll
    for (int off = 4; off < 64; off <<= 1) mx = max(mx, __shfl_xor(mx, off));
    uint2 us = *(const uint2*)(h2s + ((unsigned)nodec << 4) + q * 4);
    float a0 = bf2f((unsigned short)(us.x & 0xffff));
    float a1 = bf2f((unsigned short)(us.x >> 16));
    float a2 = bf2f((unsigned short)(us.y & 0xffff));
    float a3 = bf2f((unsigned short)(us.y >> 16));
    int clampi = deg > 0 ? deg - 1 : 0;
    int e = 0;
    for (; e + 2 <= mx; e += 2) {
        int s0 = csr[start + min(e, clampi)];
        int s1 = csr[start + min(e + 1, clampi)];
        uint2 u0 = *(const uint2*)(h2s + ((unsigned)s0 << 4) + q * 4);
        uint2 u1 = *(const uint2*)(h2s + ((unsigned)s1 << 4) + q * 4);
        if (e < deg) {
            a0 += bf2f((unsigned short)(u0.x & 0xffff));
            a1 += bf2f((unsigned short)(u0.x >> 16));
            a2 += bf2f((unsigned short)(u0.y & 0xffff));
            a3 += bf2f((unsigned short)(u0.y >> 16));
        }
        if (e + 1 < deg) {
            a0 += bf2f((unsigned short)(u1.x & 0xffff));
            a1 += bf2f((unsigned short)(u1.x >> 16));
            a2 += bf2f((unsigned short)(u1.y & 0xffff));
            a3 += bf2f((unsigned short)(u1.y >> 16));
        }
    }
    if (e < mx && e < deg) {
        int s = csr[start + e];
        uint2 u = *(const uint2*)(h2s + ((unsigned)s << 4) + q * 4);
        a0 += bf2f((unsigned short)(u.x & 0xffff));
        a1 += bf2f((unsigned short)(u.x >> 16));
        a2 += bf2f((unsigned short)(u.y & 0xffff));
        a3 += bf2f((unsigned short)(u.y >> 16));
    }
    if (valid) {
        float dv = dinv[node];
        float4 bb = *(const float4*)(b2 + q * 4);
        float4 o4 = make_float4(dv * a0 + bb.x, dv * a1 + bb.y,
                                dv * a2 + bb.z, dv * a3 + bb.w);
        *(float4*)(out + ((unsigned)node << 4) + q * 4) = o4;
    }
}

extern "C" void kernel_launch(void* const* d_in, const int* in_sizes, int n_in,
                              void* d_out, int out_size, void* d_ws, size_t ws_size,
                              hipStream_t stream) {
    const float* X  = (const float*)d_in[0];
    const int*   ei = (const int*)d_in[1];
    const float* W1 = (const float*)d_in[2];
    const float* b1 = (const float*)d_in[3];
    const float* W2 = (const float*)d_in[4];
    const float* b2 = (const float*)d_in[5];
    float* out = (float*)d_out;

    const int n = in_sizes[0] / N_FEAT_IN;   // 100000
    const int E = in_sizes[1] / 2;           // 1600000
    const int* src = ei;
    const int* dst = ei + E;

    char* ws = (char*)d_ws;
    size_t off = 0;
    auto alloc = [&](size_t bytes) -> char* {
        char* p = ws + off;
        off = (off + bytes + 255) & ~(size_t)255;
        return p;
    };
    float*          dinv    = (float*)alloc((size_t)n * 4);
    int*            row_ptr = (int*)alloc((size_t)(n + 1) * 4);
    int*            bbc     = (int*)alloc((size_t)NBUCK * NBINBLK * 4);  // 1 MB
    int*            btot    = (int*)alloc(NBUCK * 4);
    int*            bbase   = (int*)alloc((NBUCK + 1) * 4);
    int*            csr     = (int*)alloc((size_t)E * 4);
    int*            ebuf    = (int*)alloc((size_t)E * 4);                // 6.4 MB packed
    unsigned short* W1t     = (unsigned short*)alloc(128 * 256 * 2);     // 64 KB packed
    unsigned short* h1s     = (unsigned short*)alloc((size_t)(n + 1) * 128 * 2); // [8][n+1][16]
    unsigned short* tbuf    = (unsigned short*)alloc((size_t)n * 128 * 2);       // [8][n][16]
    unsigned short* h2s     = (unsigned short*)alloc((size_t)n * 16 * 2);
    int*            dcnt    = (int*)alloc((size_t)NDBIN * DBLK * 4);     // 128 KB
    int*            dtot    = (int*)alloc(NDBIN * 4);
    int*            dbase   = (int*)alloc(NDBIN * 4);
    int*            perm    = (int*)alloc((size_t)n * 4);
    (void)ws_size;

    const int NBK = (n + 127) / 128;         // 782 used buckets
    const int chunk = (E + NBINBLK - 1) / NBINBLK;
    const int nblkD = (n + 255) / 256;       // 391 degree-sort blocks

    k_bhist<<<NBINBLK, 256, 0, stream>>>(dst, bbc, E, chunk);
    k_bexscan<<<NBUCK, 256, 0, stream>>>(bbc, btot);
    k_bscan<<<1, NBUCK, 0, stream>>>(btot, bbase);
    k_bin2<<<NBINBLK, 256, 0, stream>>>(src, dst, bbc, bbase, ebuf, E, chunk);
    k_sortb<<<NBK, 256, 0, stream>>>(ebuf, bbase, row_ptr, dinv, csr, n, E);

    k_dh<<<nblkD, 256, 0, stream>>>(row_ptr, dcnt, n);
    k_dscan<<<NDBIN, 512, 0, stream>>>(dcnt, dtot, nblkD);
    k_dbase<<<1, NDBIN, 0, stream>>>(dtot, dbase);
    k_dscat<<<nblkD, 256, 0, stream>>>(row_ptr, dcnt, dbase, perm, n);

    k_prep<<<128, 256, 0, stream>>>(W1, W1t);
    k_zpad<<<1, 128, 0, stream>>>(h1s, n);
    k_gemm1<<<(n + 63) / 64, 256, 0, stream>>>(X, W1t, dinv, h1s, n);
    k_agg1<<<((n + 63) / 64) * 8, 256, 0, stream>>>(h1s, row_ptr, csr, perm, dinv, b1, tbuf, n);
    k_gemm2<<<((size_t)n * 16 + 255) / 256, 256, 0, stream>>>(tbuf, W2, dinv, h2s, n);
    k_agg2<<<(n + 63) / 64, 256, 0, stream>>>(h2s, row_ptr, csr, dinv, b2, out, n);
}

// Round 3
// 400.291 us; speedup vs baseline: 1.0193x; 1.0193x over previous
//
#include <hip/hip_runtime.h>
#include <hip/hip_bf16.h>

// SocialGNN: 2-layer GCN, N=100000 nodes, E=1600000 edges (+ self loops),
// feat 256 -> 128 (relu) -> 16.
//
// R12: agg1 = XCD-L2-resident chunked gather (R10; FETCH 77 MB verified) +
// LOCAL degree sort (rank-sort of the 64 nodes inside each block, in LDS) so
// each wave's 16 nodes have near-equal degree WITHOUT losing locality -- R11's
// global perm scattered rp/self/csr/tbuf accesses and tripled HBM fetch
// (77->301 MB, 116us). Also: 8-edge-deep gather pipeline (2-quad csr prefetch,
// shfl broadcast) for more outstanding loads in the latency-bound regime, and
// __launch_bounds__(256,8) for full occupancy (was 75%).
// History: R2 -- never funnel E atomics into <1K addresses. R4 -- bf16
// intermediates halve gather traffic. R7 -- per-wave-redundant MFMA operand
// streams from global = 2x regression. R9 -- resident-B LDS gemm1. R10 -- XCD
// chunking cuts HBM 2.4x but 16-node/wave divergence = net regression. R11 --
// GLOBAL degree sort kills locality = 301 MB fetch; sorts must be local.

typedef __attribute__((ext_vector_type(8))) short short8;
typedef __attribute__((ext_vector_type(4))) float f32x4;

__device__ inline unsigned short f2bf(float f) {
    __hip_bfloat16 h = __float2bfloat16(f);
    return *(unsigned short*)&h;
}
__device__ inline float bf2f(unsigned short u) {
    unsigned int v = ((unsigned int)u) << 16;
    return *(float*)&v;
}

#define N_FEAT_IN 256
#define NBUCK 1024     // dst>>7; used buckets = ceil(n/128) = 782
#define NBINBLK 256    // partition blocks; bbc is [NBUCK][NBINBLK]

// ---------------- partition pass 1: per-(block,bucket) LDS histogram ----------------
__global__ __launch_bounds__(256) void k_bhist(const int* __restrict__ dst,
                                               int* __restrict__ bbc, int E, int chunk) {
    __shared__ int lcnt[NBUCK];
    for (int i = threadIdx.x; i < NBUCK; i += 256) lcnt[i] = 0;
    __syncthreads();
    int start = blockIdx.x * chunk;
    int end = min(start + chunk, E);
    for (int e = start + threadIdx.x; e < end; e += 256)
        atomicAdd(&lcnt[dst[e] >> 7], 1);
    __syncthreads();
    for (int i = threadIdx.x; i < NBUCK; i += 256)
        bbc[i * NBINBLK + blockIdx.x] = lcnt[i];
}

// ---- partition pass 2: per-bucket local exclusive scan across blocks + totals ----
__global__ __launch_bounds__(256) void k_bexscan(int* __restrict__ bbc,
                                                 int* __restrict__ btot) {
    __shared__ int ts[NBINBLK];
    int bucket = blockIdx.x;
    int t = threadIdx.x;
    int v = bbc[bucket * NBINBLK + t];
    ts[t] = v; __syncthreads();
    for (int off = 1; off < NBINBLK; off <<= 1) {
        int x = (t >= off) ? ts[t - off] : 0;
        __syncthreads();
        ts[t] += x;
        __syncthreads();
    }
    bbc[bucket * NBINBLK + t] = ts[t] - v;   // local exclusive (no base yet)
    if (t == NBINBLK - 1) btot[bucket] = ts[t];
}

// ---------------- bucket-total exclusive scan -> bucket bases ----------------
__global__ __launch_bounds__(1024) void k_bscan(const int* __restrict__ btot,
                                                int* __restrict__ bbase) {
    __shared__ int ts[NBUCK];
    int t = threadIdx.x;
    int v = btot[t];
    ts[t] = v; __syncthreads();
    for (int off = 1; off < NBUCK; off <<= 1) {
        int x = (t >= off) ? ts[t - off] : 0;
        __syncthreads();
        ts[t] += x;
        __syncthreads();
    }
    bbase[t] = ts[t] - v;  // exclusive
}

// ---------------- partition pass 3: binned write (24-bit packed) ----------------
// packed edge: bits 0-16 src (n<2^17), bits 17-23 dst&127.
__global__ __launch_bounds__(256) void k_bin2(const int* __restrict__ src,
                                              const int* __restrict__ dst,
                                              const int* __restrict__ bbc,
                                              const int* __restrict__ bbase,
                                              int* __restrict__ ebuf, int E, int chunk) {
    __shared__ int lcur[NBUCK];
    for (int i = threadIdx.x; i < NBUCK; i += 256)
        lcur[i] = bbc[i * NBINBLK + blockIdx.x] + bbase[i];
    __syncthreads();
    int start = blockIdx.x * chunk;
    int end = min(start + chunk, E);
    for (int e = start + threadIdx.x; e < end; e += 256) {
        int s = src[e], d = dst[e];
        int pos = atomicAdd(&lcur[d >> 7], 1);  // LDS atomic
        ebuf[pos] = s | ((d & 127) << 17);
    }
}

// ---- per-bucket counting sort: ebuf window -> csr; also row_ptr, dinv ----
__global__ __launch_bounds__(256) void k_sortb(const int* __restrict__ ebuf,
                                               const int* __restrict__ bbase,
                                               int* __restrict__ row_ptr,
                                               float* __restrict__ dinv,
                                               int* __restrict__ csr, int n, int E) {
    __shared__ int lcnt[128];
    __shared__ int lcur[128];
    int b = blockIdx.x;
    int node0 = b << 7;
    int nodes = min(128, n - node0);
    int t = threadIdx.x;
    int s_start = bbase[b];
    int s_end = bbase[b + 1];
    if (t < 128) lcnt[t] = 0;
    __syncthreads();
    for (int e = s_start + t; e < s_end; e += 256)
        atomicAdd(&lcnt[(ebuf[e] >> 17) & 127], 1);
    __syncthreads();
    int deg = (t < 128) ? lcnt[t] : 0;
    if (t < 128) lcur[t] = deg;
    __syncthreads();
    for (int off = 1; off < 128; off <<= 1) {
        int x = 0;
        if (t < 128 && t >= off) x = lcur[t - off];
        __syncthreads();
        if (t < 128) lcur[t] += x;
        __syncthreads();
    }
    if (t < 128) {
        int excl = s_start + lcur[t] - deg;
        if (t < nodes) {
            row_ptr[node0 + t] = excl;
            dinv[node0 + t] = rsqrtf((float)deg + 1.0f);  // +1 self-loop
        }
        lcur[t] = excl;  // write cursor
    }
    if (b == 0 && t == 0) row_ptr[n] = E;
    __syncthreads();
    for (int e = s_start + t; e < s_end; e += 256) {
        int p = ebuf[e];
        int pos = atomicAdd(&lcur[(p >> 17) & 127], 1);  // LDS atomic
        csr[pos] = p & 0x1FFFF;
    }
}

// ------ W1 [256][128] f32 -> W1t packed [kq 0..31][n 0..127][j 0..7] bf16 ------
__global__ void k_prep(const float* __restrict__ W1, unsigned short* __restrict__ W1t) {
    int nn = blockIdx.x;          // 0..127
    int k = threadIdx.x;          // 0..255
    int kq = k >> 3, j = k & 7;
    W1t[kq * 1024 + nn * 8 + j] = f2bf(W1[k * 128 + nn]);
}

// ---- zero the 8 dummy rows (index n) of chunk-major h1s [8][n+1][16] ----
__global__ void k_zpad(unsigned short* __restrict__ h1s, int n) {
    int t = threadIdx.x;          // 128 threads
    int c = t >> 4, j = t & 15;
    h1s[((size_t)c * (n + 1) + n) * 16 + j] = 0;
}

// ---------------- GEMM1 (MFMA, resident-B): X[M,256]f32 @ W1 -> h1s bf16, *dinv -----
// W1 (64 KB bf16, kq-major) in LDS once; barrier-free k-loop. Epilogue stores
// CHUNK-MAJOR h1s [8][M+1][16] (chunk = col>>4) for agg1; row M is dummy-zero.
__global__ __launch_bounds__(256) void k_gemm1(const float* __restrict__ X,
                                               const unsigned short* __restrict__ W1t,
                                               const float* __restrict__ dinv,
                                               unsigned short* __restrict__ h1s, int M) {
    __shared__ unsigned short Bs[32768];   // 64 KB, [kq][n][8]
    const int tid = threadIdx.x;
    const int wv = tid >> 6;
    const int lane = tid & 63;
    const int hq = lane >> 4;       // quad 0..3
    const int l15 = lane & 15;
    const int block_row = blockIdx.x * 64;

#pragma unroll
    for (int i = 0; i < 16; ++i)
        ((uint4*)Bs)[tid + i * 256] = ((const uint4*)W1t)[tid + i * 256];
    __syncthreads();

    int arow = block_row + wv * 16 + l15;
    if (arow >= M) arow = M - 1;                       // clamp; stores masked
    const float* xp = X + (size_t)arow * 256 + hq * 8;

    f32x4 acc[8];
#pragma unroll
    for (int c = 0; c < 8; ++c) acc[c] = (f32x4){0.f, 0.f, 0.f, 0.f};

#pragma unroll
    for (int ks = 0; ks < 8; ++ks) {                   // k0 = 32*ks
        float4 a0 = *(const float4*)(xp + 32 * ks);
        float4 a1 = *(const float4*)(xp + 32 * ks + 4);
        short8 a;
        a[0] = (short)f2bf(a0.x); a[1] = (short)f2bf(a0.y);
        a[2] = (short)f2bf(a0.z); a[3] = (short)f2bf(a0.w);
        a[4] = (short)f2bf(a1.x); a[5] = (short)f2bf(a1.y);
        a[6] = (short)f2bf(a1.z); a[7] = (short)f2bf(a1.w);
        const unsigned short* bp = Bs + (ks * 4 + hq) * 1024 + l15 * 8;
#pragma unroll
        for (int c = 0; c < 8; ++c) {
            short8 b = *(const short8*)(bp + c * 128);
            acc[c] = __builtin_amdgcn_mfma_f32_16x16x32_bf16(a, b, acc[c], 0, 0, 0);
        }
    }
    // D: row = 16wv + hq*4 + r, col = c*16 + l15 -> chunk-major store
    const size_t CSTRIDE = (size_t)(M + 1) * 16;
#pragma unroll
    for (int r = 0; r < 4; ++r) {
        int row = block_row + 16 * wv + hq * 4 + r;
        if (row < M) {
            float dv = dinv[row];
#pragma unroll
            for (int c = 0; c < 8; ++c) {
                h1s[(size_t)c * CSTRIDE + (size_t)row * 16 + l15] = f2bf(acc[c][r] * dv);
            }
        }
    }
}

// ---------------- agg1 (R12): chunked gather, LOCAL degree sort, 8-deep pipe --------
// h1s chunk-major [8][n+1][16] bf16; tbuf chunk-major [8][n][16]. chunk c =
// blockIdx&7 -> XCD c; 3.2 MB slice L2-resident. Block = 64 consecutive nodes,
// rank-sorted by degree in LDS: wave w takes ranks w*16..w*16+15 -> near-equal
// degree within a wave, but all accesses stay in the block's 64-node
// neighborhood (csr contiguous ~4 KB, rp/self/tbuf 2-4 KB) -- locality kept.
// 4 lanes/node, uint2 per lane; csr coalesced (lane q loads csr[e+q]) with
// 2-quad prefetch, shfl broadcast; 8 gathers in flight per group.
__global__ __launch_bounds__(256, 8) void k_agg1(const unsigned short* __restrict__ h1s,
                                                 const int* __restrict__ rp,
                                                 const int* __restrict__ csr,
                                                 const float* __restrict__ dinv,
                                                 const float* __restrict__ b1,
                                                 unsigned short* __restrict__ tbuf, int n) {
    __shared__ int sdeg[64];
    __shared__ int sidx[64];
    const int c = blockIdx.x & 7;            // feature chunk == XCD id
    const int nb = blockIdx.x >> 3;
    const int base = nb * 64;
    const int t = threadIdx.x;

    if (t < 64) {
        int node = base + t;
        int d = 0x7FFFFFFF;                  // invalid nodes rank last
        if (node < n) d = rp[node + 1] - rp[node];
        sdeg[t] = d;
    }
    __syncthreads();
    if (t < 64) {
        int d = sdeg[t];
        int rank = 0;
#pragma unroll 8
        for (int u = 0; u < 64; ++u) {
            int du = sdeg[u];
            rank += (du < d) || (du == d && u < t);
        }
        sidx[rank] = t;
    }
    __syncthreads();

    const int w = t >> 6;
    const int lane = t & 63;
    const int g = lane >> 2;                 // group 0..15
    const int q = lane & 3;                  // lane within group
    const int gbase = lane & ~3;
    const int ib = w * 16 + g;               // rank within block
    if (base + ib >= n) return;              // ranks >= valid-count are invalid
    const int node = base + sidx[ib];

    const uint2* hv = (const uint2*)(h1s + (size_t)c * (n + 1) * 16);  // [n+1][4] uint2
    uint2 us = hv[(size_t)node * 4 + q];     // self (already *dinv)
    float a0 = bf2f((unsigned short)(us.x & 0xffff));
    float a1 = bf2f((unsigned short)(us.x >> 16));
    float a2 = bf2f((unsigned short)(us.y & 0xffff));
    float a3 = bf2f((unsigned short)(us.y >> 16));
    int e = rp[node];
    const int end = rp[node + 1];
    const int efull = e + ((end - e) & ~7);
    int p0 = (e < efull) ? csr[e + q] : 0;
    int p1 = (e < efull) ? csr[e + 4 + q] : 0;
    while (e < efull) {
        int i0 = __shfl(p0, gbase + 0);
        int i1 = __shfl(p0, gbase + 1);
        int i2 = __shfl(p0, gbase + 2);
        int i3 = __shfl(p0, gbase + 3);
        int i4 = __shfl(p1, gbase + 0);
        int i5 = __shfl(p1, gbase + 1);
        int i6 = __shfl(p1, gbase + 2);
        int i7 = __shfl(p1, gbase + 3);
        e += 8;
        p0 = (e < efull) ? csr[e + q] : 0;      // prefetch next 2 quads
        p1 = (e < efull) ? csr[e + 4 + q] : 0;
        uint2 u0 = hv[(size_t)i0 * 4 + q];
        uint2 u1 = hv[(size_t)i1 * 4 + q];
        uint2 u2 = hv[(size_t)i2 * 4 + q];
        uint2 u3 = hv[(size_t)i3 * 4 + q];
        uint2 u4 = hv[(size_t)i4 * 4 + q];
        uint2 u5 = hv[(size_t)i5 * 4 + q];
        uint2 u6 = hv[(size_t)i6 * 4 + q];
        uint2 u7 = hv[(size_t)i7 * 4 + q];
        a0 += (bf2f((unsigned short)(u0.x & 0xffff)) + bf2f((unsigned short)(u1.x & 0xffff))) +
              (bf2f((unsigned short)(u2.x & 0xffff)) + bf2f((unsigned short)(u3.x & 0xffff))) +
              (bf2f((unsigned short)(u4.x & 0xffff)) + bf2f((unsigned short)(u5.x & 0xffff))) +
              (bf2f((unsigned short)(u6.x & 0xffff)) + bf2f((unsigned short)(u7.x & 0xffff)));
        a1 += (bf2f((unsigned short)(u0.x >> 16)) + bf2f((unsigned short)(u1.x >> 16))) +
              (bf2f((unsigned short)(u2.x >> 16)) + bf2f((unsigned short)(u3.x >> 16))) +
              (bf2f((unsigned short)(u4.x >> 16)) + bf2f((unsigned short)(u5.x >> 16))) +
              (bf2f((unsigned short)(u6.x >> 16)) + bf2f((unsigned short)(u7.x >> 16)));
        a2 += (bf2f((unsigned short)(u0.y & 0xffff)) + bf2f((unsigned short)(u1.y & 0xffff))) +
              (bf2f((unsigned short)(u2.y & 0xffff)) + bf2f((unsigned short)(u3.y & 0xffff))) +
              (bf2f((unsigned short)(u4.y & 0xffff)) + bf2f((unsigned short)(u5.y & 0xffff))) +
              (bf2f((unsigned short)(u6.y & 0xffff)) + bf2f((unsigned short)(u7.y & 0xffff)));
        a3 += (bf2f((unsigned short)(u0.y >> 16)) + bf2f((unsigned short)(u1.y >> 16))) +
              (bf2f((unsigned short)(u2.y >> 16)) + bf2f((unsigned short)(u3.y >> 16))) +
              (bf2f((unsigned short)(u4.y >> 16)) + bf2f((unsigned short)(u5.y >> 16))) +
              (bf2f((unsigned short)(u6.y >> 16)) + bf2f((unsigned short)(u7.y >> 16)));
    }
    for (; e < end; ++e) {
        uint2 u = hv[(size_t)csr[e] * 4 + q];
        a0 += bf2f((unsigned short)(u.x & 0xffff));
        a1 += bf2f((unsigned short)(u.x >> 16));
        a2 += bf2f((unsigned short)(u.y & 0xffff));
        a3 += bf2f((unsigned short)(u.y >> 16));
    }
    float dv = dinv[node];
    float4 bb = *(const float4*)(b1 + c * 16 + q * 4);
    float t0 = fmaxf(dv * a0 + bb.x, 0.0f);
    float t1 = fmaxf(dv * a1 + bb.y, 0.0f);
    float t2 = fmaxf(dv * a2 + bb.z, 0.0f);
    float t3 = fmaxf(dv * a3 + bb.w, 0.0f);
    uint2 packed;
    packed.x = (unsigned int)f2bf(t0) | ((unsigned int)f2bf(t1) << 16);
    packed.y = (unsigned int)f2bf(t2) | ((unsigned int)f2bf(t3) << 16);
    ((uint2*)tbuf)[(size_t)c * n * 4 + (size_t)node * 4 + q] = packed;
}

// ---------------- GEMM2: tbuf (chunk-major [8][n][16] bf16) @ W2 -> h2s, *dinv -------
__global__ __launch_bounds__(256) void k_gemm2(const unsigned short* __restrict__ tbuf,
                                               const float* __restrict__ W2,
                                               const float* __restrict__ dinv,
                                               unsigned short* __restrict__ h2s, int n) {
    __shared__ float w2s[128 * 16];
    for (int i = threadIdx.x; i < 2048; i += 256) w2s[i] = W2[i];
    __syncthreads();
    int gid = blockIdx.x * 256 + threadIdx.x;
    int node = gid >> 4;
    int o = gid & 15;
    if (node >= n) return;
    const uint4* tv = (const uint4*)tbuf;    // chunk slice: node -> 2 uint4 (32 B)
    float acc = 0.0f;
#pragma unroll
    for (int cc = 0; cc < 8; ++cc) {
        size_t base = ((size_t)cc * n + node) * 2;
        uint4 u0 = tv[base];
        uint4 u1 = tv[base + 1];
        int k = cc * 16;
        acc += __uint_as_float(u0.x << 16) * w2s[(k + 0) * 16 + o];
        acc += __uint_as_float(u0.x & 0xffff0000u) * w2s[(k + 1) * 16 + o];
        acc += __uint_as_float(u0.y << 16) * w2s[(k + 2) * 16 + o];
        acc += __uint_as_float(u0.y & 0xffff0000u) * w2s[(k + 3) * 16 + o];
        acc += __uint_as_float(u0.z << 16) * w2s[(k + 4) * 16 + o];
        acc += __uint_as_float(u0.z & 0xffff0000u) * w2s[(k + 5) * 16 + o];
        acc += __uint_as_float(u0.w << 16) * w2s[(k + 6) * 16 + o];
        acc += __uint_as_float(u0.w & 0xffff0000u) * w2s[(k + 7) * 16 + o];
        acc += __uint_as_float(u1.x << 16) * w2s[(k + 8) * 16 + o];
        acc += __uint_as_float(u1.x & 0xffff0000u) * w2s[(k + 9) * 16 + o];
        acc += __uint_as_float(u1.y << 16) * w2s[(k + 10) * 16 + o];
        acc += __uint_as_float(u1.y & 0xffff0000u) * w2s[(k + 11) * 16 + o];
        acc += __uint_as_float(u1.z << 16) * w2s[(k + 12) * 16 + o];
        acc += __uint_as_float(u1.z & 0xffff0000u) * w2s[(k + 13) * 16 + o];
        acc += __uint_as_float(u1.w << 16) * w2s[(k + 14) * 16 + o];
        acc += __uint_as_float(u1.w & 0xffff0000u) * w2s[(k + 15) * 16 + o];
    }
    h2s[(size_t)node * 16 + o] = f2bf(acc * dinv[node]);
}

// ---------------- agg2: 4 lanes/node, uint2 (4 bf16 feats) per lane ----------------
__global__ __launch_bounds__(256) void k_agg2(const unsigned short* __restrict__ h2s,
                                              const int* __restrict__ rp,
                                              const int* __restrict__ csr,
                                              const float* __restrict__ dinv,
                                              const float* __restrict__ b2,
                                              float* __restrict__ out, int n) {
    int wid = (blockIdx.x * 256 + threadIdx.x) >> 6;
    int lane = threadIdx.x & 63;
    int slot = lane >> 2;
    int q = lane & 3;
    int node = wid * 16 + slot;
    bool valid = node < n;
    int nodec = valid ? node : n - 1;
    int start = rp[nodec];
    int deg = rp[nodec + 1] - start;
    int mx = deg;
#pragma unroll
    for (int off = 4; off < 64; off <<= 1) mx = max(mx, __shfl_xor(mx, off));
    uint2 us = *(const uint2*)(h2s + ((unsigned)nodec << 4) + q * 4);
    float a0 = bf2f((unsigned short)(us.x & 0xffff));
    float a1 = bf2f((unsigned short)(us.x >> 16));
    float a2 = bf2f((unsigned short)(us.y & 0xffff));
    float a3 = bf2f((unsigned short)(us.y >> 16));
    int clampi = deg > 0 ? deg - 1 : 0;
    int e = 0;
    for (; e + 2 <= mx; e += 2) {
        int s0 = csr[start + min(e, clampi)];
        int s1 = csr[start + min(e + 1, clampi)];
        uint2 u0 = *(const uint2*)(h2s + ((unsigned)s0 << 4) + q * 4);
        uint2 u1 = *(const uint2*)(h2s + ((unsigned)s1 << 4) + q * 4);
        if (e < deg) {
            a0 += bf2f((unsigned short)(u0.x & 0xffff));
            a1 += bf2f((unsigned short)(u0.x >> 16));
            a2 += bf2f((unsigned short)(u0.y & 0xffff));
            a3 += bf2f((unsigned short)(u0.y >> 16));
        }
        if (e + 1 < deg) {
            a0 += bf2f((unsigned short)(u1.x & 0xffff));
            a1 += bf2f((unsigned short)(u1.x >> 16));
            a2 += bf2f((unsigned short)(u1.y & 0xffff));
            a3 += bf2f((unsigned short)(u1.y >> 16));
        }
    }
    if (e < mx && e < deg) {
        int s = csr[start + e];
        uint2 u = *(const uint2*)(h2s + ((unsigned)s << 4) + q * 4);
        a0 += bf2f((unsigned short)(u.x & 0xffff));
        a1 += bf2f((unsigned short)(u.x >> 16));
        a2 += bf2f((unsigned short)(u.y & 0xffff));
        a3 += bf2f((unsigned short)(u.y >> 16));
    }
    if (valid) {
        float dv = dinv[node];
        float4 bb = *(const float4*)(b2 + q * 4);
        float4 o4 = make_float4(dv * a0 + bb.x, dv * a1 + bb.y,
                                dv * a2 + bb.z, dv * a3 + bb.w);
        *(float4*)(out + ((unsigned)node << 4) + q * 4) = o4;
    }
}

extern "C" void kernel_launch(void* const* d_in, const int* in_sizes, int n_in,
                              void* d_out, int out_size, void* d_ws, size_t ws_size,
                              hipStream_t stream) {
    const float* X  = (const float*)d_in[0];
    const int*   ei = (const int*)d_in[1];
    const float* W1 = (const float*)d_in[2];
    const float* b1 = (const float*)d_in[3];
    const float* W2 = (const float*)d_in[4];
    const float* b2 = (const float*)d_in[5];
    float* out = (float*)d_out;

    const int n = in_sizes[0] / N_FEAT_IN;   // 100000
    const int E = in_sizes[1] / 2;           // 1600000
    const int* src = ei;
    const int* dst = ei + E;

    char* ws = (char*)d_ws;
    size_t off = 0;
    auto alloc = [&](size_t bytes) -> char* {
        char* p = ws + off;
        off = (off + bytes + 255) & ~(size_t)255;
        return p;
    };
    float*          dinv    = (float*)alloc((size_t)n * 4);
    int*            row_ptr = (int*)alloc((size_t)(n + 1) * 4);
    int*            bbc     = (int*)alloc((size_t)NBUCK * NBINBLK * 4);  // 1 MB
    int*            btot    = (int*)alloc(NBUCK * 4);
    int*            bbase   = (int*)alloc((NBUCK + 1) * 4);
    int*            csr     = (int*)alloc((size_t)E * 4);
    int*            ebuf    = (int*)alloc((size_t)E * 4);                // 6.4 MB packed
    unsigned short* W1t     = (unsigned short*)alloc(128 * 256 * 2);     // 64 KB packed
    unsigned short* h1s     = (unsigned short*)alloc((size_t)(n + 1) * 128 * 2); // [8][n+1][16]
    unsigned short* tbuf    = (unsigned short*)alloc((size_t)n * 128 * 2);       // [8][n][16]
    unsigned short* h2s     = (unsigned short*)alloc((size_t)n * 16 * 2);
    (void)ws_size;

    const int NBK = (n + 127) / 128;         // 782 used buckets
    const int chunk = (E + NBINBLK - 1) / NBINBLK;

    k_bhist<<<NBINBLK, 256, 0, stream>>>(dst, bbc, E, chunk);
    k_bexscan<<<NBUCK, 256, 0, stream>>>(bbc, btot);
    k_bscan<<<1, NBUCK, 0, stream>>>(btot, bbase);
    k_bin2<<<NBINBLK, 256, 0, stream>>>(src, dst, bbc, bbase, ebuf, E, chunk);
    k_sortb<<<NBK, 256, 0, stream>>>(ebuf, bbase, row_ptr, dinv, csr, n, E);

    k_prep<<<128, 256, 0, stream>>>(W1, W1t);
    k_zpad<<<1, 128, 0, stream>>>(h1s, n);
    k_gemm1<<<(n + 63) / 64, 256, 0, stream>>>(X, W1t, dinv, h1s, n);
    k_agg1<<<((n + 63) / 64) * 8, 256, 0, stream>>>(h1s, row_ptr, csr, dinv, b1, tbuf, n);
    k_gemm2<<<((size_t)n * 16 + 255) / 256, 256, 0, stream>>>(tbuf, W2, dinv, h2s, n);
    k_agg2<<<(n + 63) / 64, 256, 0, stream>>>(h2s, row_ptr, csr, dinv, b2, out, n);
}

// Round 4
// 392.768 us; speedup vs baseline: 1.0389x; 1.0192x over previous
//
#include <hip/hip_runtime.h>
#include <hip/hip_bf16.h>

// SocialGNN: 2-layer GCN, N=100000 nodes, E=1600000 edges (+ self loops),
// feat 256 -> 128 (relu) -> 16.
//
// R13: agg1 = XCD-L2-resident chunked gather (R10 layout, FETCH 77 MB
// verified) with SEQUENTIAL node order (no reordering of any kind) + 8-deep
// gather pipeline (2-quad coalesced csr prefetch + shfl broadcast) +
// __launch_bounds__(256,8). R10's 85us was latency exposure (1-deep pipe),
// not request tax (model: ~21us tax x1.6 divergence = 35us floor).
// History: R2 -- never funnel E atomics into <1K addresses. R4 -- bf16
// intermediates halve gather traffic. R7 -- per-wave-redundant MFMA operand
// streams from global = 2x regression. R9 -- resident-B LDS gemm1. R10 -- XCD
// chunking cuts HBM 2.4x (188->77 MB). R11 -- GLOBAL degree sort kills
// locality (301 MB fetch). R12 -- even LOCAL rank-sort scatters the 32-B tbuf
// stores -> RFO+write-amp (WRITE 25->121 MB) thrashes the resident L2 slice.
// NODE REORDERING IS DEAD; divergence must be paid or hidden, not sorted away.

typedef __attribute__((ext_vector_type(8))) short short8;
typedef __attribute__((ext_vector_type(4))) float f32x4;

__device__ inline unsigned short f2bf(float f) {
    __hip_bfloat16 h = __float2bfloat16(f);
    return *(unsigned short*)&h;
}
__device__ inline float bf2f(unsigned short u) {
    unsigned int v = ((unsigned int)u) << 16;
    return *(float*)&v;
}

#define N_FEAT_IN 256
#define NBUCK 1024     // dst>>7; used buckets = ceil(n/128) = 782
#define NBINBLK 256    // partition blocks; bbc is [NBUCK][NBINBLK]

// ---------------- partition pass 1: per-(block,bucket) LDS histogram ----------------
__global__ __launch_bounds__(256) void k_bhist(const int* __restrict__ dst,
                                               int* __restrict__ bbc, int E, int chunk) {
    __shared__ int lcnt[NBUCK];
    for (int i = threadIdx.x; i < NBUCK; i += 256) lcnt[i] = 0;
    __syncthreads();
    int start = blockIdx.x * chunk;
    int end = min(start + chunk, E);
    for (int e = start + threadIdx.x; e < end; e += 256)
        atomicAdd(&lcnt[dst[e] >> 7], 1);
    __syncthreads();
    for (int i = threadIdx.x; i < NBUCK; i += 256)
        bbc[i * NBINBLK + blockIdx.x] = lcnt[i];
}

// ---- partition pass 2: per-bucket local exclusive scan across blocks + totals ----
__global__ __launch_bounds__(256) void k_bexscan(int* __restrict__ bbc,
                                                 int* __restrict__ btot) {
    __shared__ int ts[NBINBLK];
    int bucket = blockIdx.x;
    int t = threadIdx.x;
    int v = bbc[bucket * NBINBLK + t];
    ts[t] = v; __syncthreads();
    for (int off = 1; off < NBINBLK; off <<= 1) {
        int x = (t >= off) ? ts[t - off] : 0;
        __syncthreads();
        ts[t] += x;
        __syncthreads();
    }
    bbc[bucket * NBINBLK + t] = ts[t] - v;   // local exclusive (no base yet)
    if (t == NBINBLK - 1) btot[bucket] = ts[t];
}

// ---------------- bucket-total exclusive scan -> bucket bases ----------------
__global__ __launch_bounds__(1024) void k_bscan(const int* __restrict__ btot,
                                                int* __restrict__ bbase) {
    __shared__ int ts[NBUCK];
    int t = threadIdx.x;
    int v = btot[t];
    ts[t] = v; __syncthreads();
    for (int off = 1; off < NBUCK; off <<= 1) {
        int x = (t >= off) ? ts[t - off] : 0;
        __syncthreads();
        ts[t] += x;
        __syncthreads();
    }
    bbase[t] = ts[t] - v;  // exclusive
}

// ---------------- partition pass 3: binned write (24-bit packed) ----------------
// packed edge: bits 0-16 src (n<2^17), bits 17-23 dst&127.
__global__ __launch_bounds__(256) void k_bin2(const int* __restrict__ src,
                                              const int* __restrict__ dst,
                                              const int* __restrict__ bbc,
                                              const int* __restrict__ bbase,
                                              int* __restrict__ ebuf, int E, int chunk) {
    __shared__ int lcur[NBUCK];
    for (int i = threadIdx.x; i < NBUCK; i += 256)
        lcur[i] = bbc[i * NBINBLK + blockIdx.x] + bbase[i];
    __syncthreads();
    int start = blockIdx.x * chunk;
    int end = min(start + chunk, E);
    for (int e = start + threadIdx.x; e < end; e += 256) {
        int s = src[e], d = dst[e];
        int pos = atomicAdd(&lcur[d >> 7], 1);  // LDS atomic
        ebuf[pos] = s | ((d & 127) << 17);
    }
}

// ---- per-bucket counting sort: ebuf window -> csr; also row_ptr, dinv ----
__global__ __launch_bounds__(256) void k_sortb(const int* __restrict__ ebuf,
                                               const int* __restrict__ bbase,
                                               int* __restrict__ row_ptr,
                                               float* __restrict__ dinv,
                                               int* __restrict__ csr, int n, int E) {
    __shared__ int lcnt[128];
    __shared__ int lcur[128];
    int b = blockIdx.x;
    int node0 = b << 7;
    int nodes = min(128, n - node0);
    int t = threadIdx.x;
    int s_start = bbase[b];
    int s_end = bbase[b + 1];
    if (t < 128) lcnt[t] = 0;
    __syncthreads();
    for (int e = s_start + t; e < s_end; e += 256)
        atomicAdd(&lcnt[(ebuf[e] >> 17) & 127], 1);
    __syncthreads();
    int deg = (t < 128) ? lcnt[t] : 0;
    if (t < 128) lcur[t] = deg;
    __syncthreads();
    for (int off = 1; off < 128; off <<= 1) {
        int x = 0;
        if (t < 128 && t >= off) x = lcur[t - off];
        __syncthreads();
        if (t < 128) lcur[t] += x;
        __syncthreads();
    }
    if (t < 128) {
        int excl = s_start + lcur[t] - deg;
        if (t < nodes) {
            row_ptr[node0 + t] = excl;
            dinv[node0 + t] = rsqrtf((float)deg + 1.0f);  // +1 self-loop
        }
        lcur[t] = excl;  // write cursor
    }
    if (b == 0 && t == 0) row_ptr[n] = E;
    __syncthreads();
    for (int e = s_start + t; e < s_end; e += 256) {
        int p = ebuf[e];
        int pos = atomicAdd(&lcur[(p >> 17) & 127], 1);  // LDS atomic
        csr[pos] = p & 0x1FFFF;
    }
}

// ------ W1 [256][128] f32 -> W1t packed [kq 0..31][n 0..127][j 0..7] bf16 ------
__global__ void k_prep(const float* __restrict__ W1, unsigned short* __restrict__ W1t) {
    int nn = blockIdx.x;          // 0..127
    int k = threadIdx.x;          // 0..255
    int kq = k >> 3, j = k & 7;
    W1t[kq * 1024 + nn * 8 + j] = f2bf(W1[k * 128 + nn]);
}

// ---- zero the 8 dummy rows (index n) of chunk-major h1s [8][n+1][16] ----
__global__ void k_zpad(unsigned short* __restrict__ h1s, int n) {
    int t = threadIdx.x;          // 128 threads
    int c = t >> 4, j = t & 15;
    h1s[((size_t)c * (n + 1) + n) * 16 + j] = 0;
}

// ---------------- GEMM1 (MFMA, resident-B): X[M,256]f32 @ W1 -> h1s bf16, *dinv -----
// W1 (64 KB bf16, kq-major) in LDS once; barrier-free k-loop. Epilogue stores
// CHUNK-MAJOR h1s [8][M+1][16] (chunk = col>>4) for agg1; row M is dummy-zero.
__global__ __launch_bounds__(256) void k_gemm1(const float* __restrict__ X,
                                               const unsigned short* __restrict__ W1t,
                                               const float* __restrict__ dinv,
                                               unsigned short* __restrict__ h1s, int M) {
    __shared__ unsigned short Bs[32768];   // 64 KB, [kq][n][8]
    const int tid = threadIdx.x;
    const int wv = tid >> 6;
    const int lane = tid & 63;
    const int hq = lane >> 4;       // quad 0..3
    const int l15 = lane & 15;
    const int block_row = blockIdx.x * 64;

#pragma unroll
    for (int i = 0; i < 16; ++i)
        ((uint4*)Bs)[tid + i * 256] = ((const uint4*)W1t)[tid + i * 256];
    __syncthreads();

    int arow = block_row + wv * 16 + l15;
    if (arow >= M) arow = M - 1;                       // clamp; stores masked
    const float* xp = X + (size_t)arow * 256 + hq * 8;

    f32x4 acc[8];
#pragma unroll
    for (int c = 0; c < 8; ++c) acc[c] = (f32x4){0.f, 0.f, 0.f, 0.f};

#pragma unroll
    for (int ks = 0; ks < 8; ++ks) {                   // k0 = 32*ks
        float4 a0 = *(const float4*)(xp + 32 * ks);
        float4 a1 = *(const float4*)(xp + 32 * ks + 4);
        short8 a;
        a[0] = (short)f2bf(a0.x); a[1] = (short)f2bf(a0.y);
        a[2] = (short)f2bf(a0.z); a[3] = (short)f2bf(a0.w);
        a[4] = (short)f2bf(a1.x); a[5] = (short)f2bf(a1.y);
        a[6] = (short)f2bf(a1.z); a[7] = (short)f2bf(a1.w);
        const unsigned short* bp = Bs + (ks * 4 + hq) * 1024 + l15 * 8;
#pragma unroll
        for (int c = 0; c < 8; ++c) {
            short8 b = *(const short8*)(bp + c * 128);
            acc[c] = __builtin_amdgcn_mfma_f32_16x16x32_bf16(a, b, acc[c], 0, 0, 0);
        }
    }
    // D: row = 16wv + hq*4 + r, col = c*16 + l15 -> chunk-major store
    const size_t CSTRIDE = (size_t)(M + 1) * 16;
#pragma unroll
    for (int r = 0; r < 4; ++r) {
        int row = block_row + 16 * wv + hq * 4 + r;
        if (row < M) {
            float dv = dinv[row];
#pragma unroll
            for (int c = 0; c < 8; ++c) {
                h1s[(size_t)c * CSTRIDE + (size_t)row * 16 + l15] = f2bf(acc[c][r] * dv);
            }
        }
    }
}

// ---------------- agg1 (R13): chunked gather, sequential nodes, 8-deep pipe --------
// h1s chunk-major [8][n+1][16] bf16; tbuf chunk-major [8][n][16]. chunk c =
// blockIdx&7 -> XCD c; 3.2 MB slice L2-resident. Block = 64 consecutive nodes
// in natural order (reordering poisons store coalescing -- R11/R12). 4
// lanes/node, uint2 per lane; csr coalesced (lane q loads csr[e+q]) with
// 2-quad prefetch + shfl broadcast: 8 gathers in flight per group.
__global__ __launch_bounds__(256, 8) void k_agg1(const unsigned short* __restrict__ h1s,
                                                 const int* __restrict__ rp,
                                                 const int* __restrict__ csr,
                                                 const float* __restrict__ dinv,
                                                 const float* __restrict__ b1,
                                                 unsigned short* __restrict__ tbuf, int n) {
    const int c = blockIdx.x & 7;            // feature chunk == XCD id
    const int nb = blockIdx.x >> 3;
    const int node = nb * 64 + (threadIdx.x >> 2);
    const int lane = threadIdx.x & 63;
    const int q = threadIdx.x & 3;           // lane within 4-lane node group
    const int gbase = lane & ~3;             // group's base lane in wave
    if (node >= n) return;

    const uint2* hv = (const uint2*)(h1s + (size_t)c * (n + 1) * 16);  // [n+1][4] uint2
    uint2 us = hv[(size_t)node * 4 + q];     // self (already *dinv)
    float a0 = bf2f((unsigned short)(us.x & 0xffff));
    float a1 = bf2f((unsigned short)(us.x >> 16));
    float a2 = bf2f((unsigned short)(us.y & 0xffff));
    float a3 = bf2f((unsigned short)(us.y >> 16));
    int e = rp[node];
    const int end = rp[node + 1];
    const int efull = e + ((end - e) & ~7);
    int p0 = (e < efull) ? csr[e + q] : 0;
    int p1 = (e < efull) ? csr[e + 4 + q] : 0;
    while (e < efull) {
        int i0 = __shfl(p0, gbase + 0);
        int i1 = __shfl(p0, gbase + 1);
        int i2 = __shfl(p0, gbase + 2);
        int i3 = __shfl(p0, gbase + 3);
        int i4 = __shfl(p1, gbase + 0);
        int i5 = __shfl(p1, gbase + 1);
        int i6 = __shfl(p1, gbase + 2);
        int i7 = __shfl(p1, gbase + 3);
        e += 8;
        p0 = (e < efull) ? csr[e + q] : 0;      // prefetch next 2 quads
        p1 = (e < efull) ? csr[e + 4 + q] : 0;
        uint2 u0 = hv[(size_t)i0 * 4 + q];
        uint2 u1 = hv[(size_t)i1 * 4 + q];
        uint2 u2 = hv[(size_t)i2 * 4 + q];
        uint2 u3 = hv[(size_t)i3 * 4 + q];
        uint2 u4 = hv[(size_t)i4 * 4 + q];
        uint2 u5 = hv[(size_t)i5 * 4 + q];
        uint2 u6 = hv[(size_t)i6 * 4 + q];
        uint2 u7 = hv[(size_t)i7 * 4 + q];
        a0 += (bf2f((unsigned short)(u0.x & 0xffff)) + bf2f((unsigned short)(u1.x & 0xffff))) +
              (bf2f((unsigned short)(u2.x & 0xffff)) + bf2f((unsigned short)(u3.x & 0xffff))) +
              (bf2f((unsigned short)(u4.x & 0xffff)) + bf2f((unsigned short)(u5.x & 0xffff))) +
              (bf2f((unsigned short)(u6.x & 0xffff)) + bf2f((unsigned short)(u7.x & 0xffff)));
        a1 += (bf2f((unsigned short)(u0.x >> 16)) + bf2f((unsigned short)(u1.x >> 16))) +
              (bf2f((unsigned short)(u2.x >> 16)) + bf2f((unsigned short)(u3.x >> 16))) +
              (bf2f((unsigned short)(u4.x >> 16)) + bf2f((unsigned short)(u5.x >> 16))) +
              (bf2f((unsigned short)(u6.x >> 16)) + bf2f((unsigned short)(u7.x >> 16)));
        a2 += (bf2f((unsigned short)(u0.y & 0xffff)) + bf2f((unsigned short)(u1.y & 0xffff))) +
              (bf2f((unsigned short)(u2.y & 0xffff)) + bf2f((unsigned short)(u3.y & 0xffff))) +
              (bf2f((unsigned short)(u4.y & 0xffff)) + bf2f((unsigned short)(u5.y & 0xffff))) +
              (bf2f((unsigned short)(u6.y & 0xffff)) + bf2f((unsigned short)(u7.y & 0xffff)));
        a3 += (bf2f((unsigned short)(u0.y >> 16)) + bf2f((unsigned short)(u1.y >> 16))) +
              (bf2f((unsigned short)(u2.y >> 16)) + bf2f((unsigned short)(u3.y >> 16))) +
              (bf2f((unsigned short)(u4.y >> 16)) + bf2f((unsigned short)(u5.y >> 16))) +
              (bf2f((unsigned short)(u6.y >> 16)) + bf2f((unsigned short)(u7.y >> 16)));
    }
    for (; e < end; ++e) {
        uint2 u = hv[(size_t)csr[e] * 4 + q];
        a0 += bf2f((unsigned short)(u.x & 0xffff));
        a1 += bf2f((unsigned short)(u.x >> 16));
        a2 += bf2f((unsigned short)(u.y & 0xffff));
        a3 += bf2f((unsigned short)(u.y >> 16));
    }
    float dv = dinv[node];
    float4 bb = *(const float4*)(b1 + c * 16 + q * 4);
    float t0 = fmaxf(dv * a0 + bb.x, 0.0f);
    float t1 = fmaxf(dv * a1 + bb.y, 0.0f);
    float t2 = fmaxf(dv * a2 + bb.z, 0.0f);
    float t3 = fmaxf(dv * a3 + bb.w, 0.0f);
    uint2 packed;
    packed.x = (unsigned int)f2bf(t0) | ((unsigned int)f2bf(t1) << 16);
    packed.y = (unsigned int)f2bf(t2) | ((unsigned int)f2bf(t3) << 16);
    ((uint2*)tbuf)[(size_t)c * n * 4 + (size_t)node * 4 + q] = packed;
}

// ---------------- GEMM2: tbuf (chunk-major [8][n][16] bf16) @ W2 -> h2s, *dinv -------
__global__ __launch_bounds__(256) void k_gemm2(const unsigned short* __restrict__ tbuf,
                                               const float* __restrict__ W2,
                                               const float* __restrict__ dinv,
                                               unsigned short* __restrict__ h2s, int n) {
    __shared__ float w2s[128 * 16];
    for (int i = threadIdx.x; i < 2048; i += 256) w2s[i] = W2[i];
    __syncthreads();
    int gid = blockIdx.x * 256 + threadIdx.x;
    int node = gid >> 4;
    int o = gid & 15;
    if (node >= n) return;
    const uint4* tv = (const uint4*)tbuf;    // chunk slice: node -> 2 uint4 (32 B)
    float acc = 0.0f;
#pragma unroll
    for (int cc = 0; cc < 8; ++cc) {
        size_t base = ((size_t)cc * n + node) * 2;
        uint4 u0 = tv[base];
        uint4 u1 = tv[base + 1];
        int k = cc * 16;
        acc += __uint_as_float(u0.x << 16) * w2s[(k + 0) * 16 + o];
        acc += __uint_as_float(u0.x & 0xffff0000u) * w2s[(k + 1) * 16 + o];
        acc += __uint_as_float(u0.y << 16) * w2s[(k + 2) * 16 + o];
        acc += __uint_as_float(u0.y & 0xffff0000u) * w2s[(k + 3) * 16 + o];
        acc += __uint_as_float(u0.z << 16) * w2s[(k + 4) * 16 + o];
        acc += __uint_as_float(u0.z & 0xffff0000u) * w2s[(k + 5) * 16 + o];
        acc += __uint_as_float(u0.w << 16) * w2s[(k + 6) * 16 + o];
        acc += __uint_as_float(u0.w & 0xffff0000u) * w2s[(k + 7) * 16 + o];
        acc += __uint_as_float(u1.x << 16) * w2s[(k + 8) * 16 + o];
        acc += __uint_as_float(u1.x & 0xffff0000u) * w2s[(k + 9) * 16 + o];
        acc += __uint_as_float(u1.y << 16) * w2s[(k + 10) * 16 + o];
        acc += __uint_as_float(u1.y & 0xffff0000u) * w2s[(k + 11) * 16 + o];
        acc += __uint_as_float(u1.z << 16) * w2s[(k + 12) * 16 + o];
        acc += __uint_as_float(u1.z & 0xffff0000u) * w2s[(k + 13) * 16 + o];
        acc += __uint_as_float(u1.w << 16) * w2s[(k + 14) * 16 + o];
        acc += __uint_as_float(u1.w & 0xffff0000u) * w2s[(k + 15) * 16 + o];
    }
    h2s[(size_t)node * 16 + o] = f2bf(acc * dinv[node]);
}

// ---------------- agg2: 4 lanes/node, uint2 (4 bf16 feats) per lane ----------------
__global__ __launch_bounds__(256) void k_agg2(const unsigned short* __restrict__ h2s,
                                              const int* __restrict__ rp,
                                              const int* __restrict__ csr,
                                              const float* __restrict__ dinv,
                                              const float* __restrict__ b2,
                                              float* __restrict__ out, int n) {
    int wid = (blockIdx.x * 256 + threadIdx.x) >> 6;
    int lane = threadIdx.x & 63;
    int slot = lane >> 2;
    int q = lane & 3;
    int node = wid * 16 + slot;
    bool valid = node < n;
    int nodec = valid ? node : n - 1;
    int start = rp[nodec];
    int deg = rp[nodec + 1] - start;
    int mx = deg;
#pragma unroll
    for (int off = 4; off < 64; off <<= 1) mx = max(mx, __shfl_xor(mx, off));
    uint2 us = *(const uint2*)(h2s + ((unsigned)nodec << 4) + q * 4);
    float a0 = bf2f((unsigned short)(us.x & 0xffff));
    float a1 = bf2f((unsigned short)(us.x >> 16));
    float a2 = bf2f((unsigned short)(us.y & 0xffff));
    float a3 = bf2f((unsigned short)(us.y >> 16));
    int clampi = deg > 0 ? deg - 1 : 0;
    int e = 0;
    for (; e + 2 <= mx; e += 2) {
        int s0 = csr[start + min(e, clampi)];
        int s1 = csr[start + min(e + 1, clampi)];
        uint2 u0 = *(const uint2*)(h2s + ((unsigned)s0 << 4) + q * 4);
        uint2 u1 = *(const uint2*)(h2s + ((unsigned)s1 << 4) + q * 4);
        if (e < deg) {
            a0 += bf2f((unsigned short)(u0.x & 0xffff));
            a1 += bf2f((unsigned short)(u0.x >> 16));
            a2 += bf2f((unsigned short)(u0.y & 0xffff));
            a3 += bf2f((unsigned short)(u0.y >> 16));
        }
        if (e + 1 < deg) {
            a0 += bf2f((unsigned short)(u1.x & 0xffff));
            a1 += bf2f((unsigned short)(u1.x >> 16));
            a2 += bf2f((unsigned short)(u1.y & 0xffff));
            a3 += bf2f((unsigned short)(u1.y >> 16));
        }
    }
    if (e < mx && e < deg) {
        int s = csr[start + e];
        uint2 u = *(const uint2*)(h2s + ((unsigned)s << 4) + q * 4);
        a0 += bf2f((unsigned short)(u.x & 0xffff));
        a1 += bf2f((unsigned short)(u.x >> 16));
        a2 += bf2f((unsigned short)(u.y & 0xffff));
        a3 += bf2f((unsigned short)(u.y >> 16));
    }
    if (valid) {
        float dv = dinv[node];
        float4 bb = *(const float4*)(b2 + q * 4);
        float4 o4 = make_float4(dv * a0 + bb.x, dv * a1 + bb.y,
                                dv * a2 + bb.z, dv * a3 + bb.w);
        *(float4*)(out + ((unsigned)node << 4) + q * 4) = o4;
    }
}

extern "C" void kernel_launch(void* const* d_in, const int* in_sizes, int n_in,
                              void* d_out, int out_size, void* d_ws, size_t ws_size,
                              hipStream_t stream) {
    const float* X  = (const float*)d_in[0];
    const int*   ei = (const int*)d_in[1];
    const float* W1 = (const float*)d_in[2];
    const float* b1 = (const float*)d_in[3];
    const float* W2 = (const float*)d_in[4];
    const float* b2 = (const float*)d_in[5];
    float* out = (float*)d_out;

    const int n = in_sizes[0] / N_FEAT_IN;   // 100000
    const int E = in_sizes[1] / 2;           // 1600000
    const int* src = ei;
    const int* dst = ei + E;

    char* ws = (char*)d_ws;
    size_t off = 0;
    auto alloc = [&](size_t bytes) -> char* {
        char* p = ws + off;
        off = (off + bytes + 255) & ~(size_t)255;
        return p;
    };
    float*          dinv    = (float*)alloc((size_t)n * 4);
    int*            row_ptr = (int*)alloc((size_t)(n + 1) * 4);
    int*            bbc     = (int*)alloc((size_t)NBUCK * NBINBLK * 4);  // 1 MB
    int*            btot    = (int*)alloc(NBUCK * 4);
    int*            bbase   = (int*)alloc((NBUCK + 1) * 4);
    int*            csr     = (int*)alloc((size_t)E * 4);
    int*            ebuf    = (int*)alloc((size_t)E * 4);                // 6.4 MB packed
    unsigned short* W1t     = (unsigned short*)alloc(128 * 256 * 2);     // 64 KB packed
    unsigned short* h1s     = (unsigned short*)alloc((size_t)(n + 1) * 128 * 2); // [8][n+1][16]
    unsigned short* tbuf    = (unsigned short*)alloc((size_t)n * 128 * 2);       // [8][n][16]
    unsigned short* h2s     = (unsigned short*)alloc((size_t)n * 16 * 2);
    (void)ws_size;

    const int NBK = (n + 127) / 128;         // 782 used buckets
    const int chunk = (E + NBINBLK - 1) / NBINBLK;

    k_bhist<<<NBINBLK, 256, 0, stream>>>(dst, bbc, E, chunk);
    k_bexscan<<<NBUCK, 256, 0, stream>>>(bbc, btot);
    k_bscan<<<1, NBUCK, 0, stream>>>(btot, bbase);
    k_bin2<<<NBINBLK, 256, 0, stream>>>(src, dst, bbc, bbase, ebuf, E, chunk);
    k_sortb<<<NBK, 256, 0, stream>>>(ebuf, bbase, row_ptr, dinv, csr, n, E);

    k_prep<<<128, 256, 0, stream>>>(W1, W1t);
    k_zpad<<<1, 128, 0, stream>>>(h1s, n);
    k_gemm1<<<(n + 63) / 64, 256, 0, stream>>>(X, W1t, dinv, h1s, n);
    k_agg1<<<((n + 63) / 64) * 8, 256, 0, stream>>>(h1s, row_ptr, csr, dinv, b1, tbuf, n);
    k_gemm2<<<((size_t)n * 16 + 255) / 256, 256, 0, stream>>>(tbuf, W2, dinv, h2s, n);
    k_agg2<<<(n + 63) / 64, 256, 0, stream>>>(h2s, row_ptr, csr, dinv, b2, out, n);
}

// Round 5
// 343.369 us; speedup vs baseline: 1.1883x; 1.1439x over previous
//
#include <hip/hip_runtime.h>
#include <hip/hip_bf16.h>

// SocialGNN: 2-layer GCN, N=100000 nodes, E=1600000 edges (+ self loops),
// feat 256 -> 128 (relu) -> 16.
//
// R14: full revert to the proven R9 pipeline (344.7us; agg1 64us, F=188MB,
// W=25MB) + ONE delta: agg1's edge loop deepened 4->8 (8 gathers in flight
// per wave, same layout, same streams) to close the latency-exposure gap
// (agg1 ran 2.9 TB/s vs 6.3 achievable).
// History: R2 -- never funnel E atomics into <1K addresses. R4 -- bf16
// intermediates halve gather traffic. R7 -- per-wave-redundant MFMA operand
// streams from global = 2x regression. R9 -- resident-B LDS gemm1 (W1 64KB in
// LDS once, barrier-free k-loop). R10-R13 -- XCD feature-chunking branch
// ABANDONED: chunking cut HBM 2.4x but its best-case floor (VALU 31us + TA
// 21us + divergence) merely matches R9's 64us, and every variant regressed
// (divergence 85us / global sort 301MB fetch / local sort + LB(256,8) write
// amplification 112-121MB, mechanism unexplained). Node reordering poisons
// store coalescing; chunked-gather has no headroom over row-major here.

typedef __attribute__((ext_vector_type(8))) short short8;
typedef __attribute__((ext_vector_type(4))) float f32x4;

__device__ inline unsigned short f2bf(float f) {
    __hip_bfloat16 h = __float2bfloat16(f);
    return *(unsigned short*)&h;
}
__device__ inline float bf2f(unsigned short u) {
    unsigned int v = ((unsigned int)u) << 16;
    return *(float*)&v;
}

#define N_FEAT_IN 256
#define NBUCK 1024     // dst>>7; used buckets = ceil(n/128) = 782
#define NBINBLK 256    // partition blocks; bbc is [NBUCK][NBINBLK]

// ---------------- partition pass 1: per-(block,bucket) LDS histogram ----------------
__global__ __launch_bounds__(256) void k_bhist(const int* __restrict__ dst,
                                               int* __restrict__ bbc, int E, int chunk) {
    __shared__ int lcnt[NBUCK];
    for (int i = threadIdx.x; i < NBUCK; i += 256) lcnt[i] = 0;
    __syncthreads();
    int start = blockIdx.x * chunk;
    int end = min(start + chunk, E);
    for (int e = start + threadIdx.x; e < end; e += 256)
        atomicAdd(&lcnt[dst[e] >> 7], 1);
    __syncthreads();
    for (int i = threadIdx.x; i < NBUCK; i += 256)
        bbc[i * NBINBLK + blockIdx.x] = lcnt[i];
}

// ---- partition pass 2: per-bucket local exclusive scan across blocks + totals ----
__global__ __launch_bounds__(256) void k_bexscan(int* __restrict__ bbc,
                                                 int* __restrict__ btot) {
    __shared__ int ts[NBINBLK];
    int bucket = blockIdx.x;
    int t = threadIdx.x;
    int v = bbc[bucket * NBINBLK + t];
    ts[t] = v; __syncthreads();
    for (int off = 1; off < NBINBLK; off <<= 1) {
        int x = (t >= off) ? ts[t - off] : 0;
        __syncthreads();
        ts[t] += x;
        __syncthreads();
    }
    bbc[bucket * NBINBLK + t] = ts[t] - v;   // local exclusive (no base yet)
    if (t == NBINBLK - 1) btot[bucket] = ts[t];
}

// ---------------- bucket-total exclusive scan -> bucket bases ----------------
__global__ __launch_bounds__(1024) void k_bscan(const int* __restrict__ btot,
                                                int* __restrict__ bbase) {
    __shared__ int ts[NBUCK];
    int t = threadIdx.x;
    int v = btot[t];
    ts[t] = v; __syncthreads();
    for (int off = 1; off < NBUCK; off <<= 1) {
        int x = (t >= off) ? ts[t - off] : 0;
        __syncthreads();
        ts[t] += x;
        __syncthreads();
    }
    bbase[t] = ts[t] - v;  // exclusive
}

// ---------------- partition pass 3: binned write (24-bit packed) ----------------
// packed edge: bits 0-16 src (n<2^17), bits 17-23 dst&127.
__global__ __launch_bounds__(256) void k_bin2(const int* __restrict__ src,
                                              const int* __restrict__ dst,
                                              const int* __restrict__ bbc,
                                              const int* __restrict__ bbase,
                                              int* __restrict__ ebuf, int E, int chunk) {
    __shared__ int lcur[NBUCK];
    for (int i = threadIdx.x; i < NBUCK; i += 256)
        lcur[i] = bbc[i * NBINBLK + blockIdx.x] + bbase[i];
    __syncthreads();
    int start = blockIdx.x * chunk;
    int end = min(start + chunk, E);
    for (int e = start + threadIdx.x; e < end; e += 256) {
        int s = src[e], d = dst[e];
        int pos = atomicAdd(&lcur[d >> 7], 1);  // LDS atomic
        ebuf[pos] = s | ((d & 127) << 17);
    }
}

// ---- per-bucket counting sort: ebuf window -> csr; also row_ptr, dinv ----
__global__ __launch_bounds__(256) void k_sortb(const int* __restrict__ ebuf,
                                               const int* __restrict__ bbase,
                                               int* __restrict__ row_ptr,
                                               float* __restrict__ dinv,
                                               int* __restrict__ csr, int n, int E) {
    __shared__ int lcnt[128];
    __shared__ int lcur[128];
    int b = blockIdx.x;
    int node0 = b << 7;
    int nodes = min(128, n - node0);
    int t = threadIdx.x;
    int s_start = bbase[b];
    int s_end = bbase[b + 1];
    if (t < 128) lcnt[t] = 0;
    __syncthreads();
    for (int e = s_start + t; e < s_end; e += 256)
        atomicAdd(&lcnt[(ebuf[e] >> 17) & 127], 1);
    __syncthreads();
    int deg = (t < 128) ? lcnt[t] : 0;
    if (t < 128) lcur[t] = deg;
    __syncthreads();
    for (int off = 1; off < 128; off <<= 1) {
        int x = 0;
        if (t < 128 && t >= off) x = lcur[t - off];
        __syncthreads();
        if (t < 128) lcur[t] += x;
        __syncthreads();
    }
    if (t < 128) {
        int excl = s_start + lcur[t] - deg;
        if (t < nodes) {
            row_ptr[node0 + t] = excl;
            dinv[node0 + t] = rsqrtf((float)deg + 1.0f);  // +1 self-loop
        }
        lcur[t] = excl;  // write cursor
    }
    if (b == 0 && t == 0) row_ptr[n] = E;
    __syncthreads();
    for (int e = s_start + t; e < s_end; e += 256) {
        int p = ebuf[e];
        int pos = atomicAdd(&lcur[(p >> 17) & 127], 1);  // LDS atomic
        csr[pos] = p & 0x1FFFF;
    }
}

// ------ W1 [256][128] f32 -> W1t packed [kq 0..31][n 0..127][j 0..7] bf16 ------
// element (n, k=kq*8+j) lives at W1t[kq*1024 + n*8 + j].
__global__ void k_prep(const float* __restrict__ W1, unsigned short* __restrict__ W1t) {
    int nn = blockIdx.x;          // 0..127
    int k = threadIdx.x;          // 0..255
    int kq = k >> 3, j = k & 7;
    W1t[kq * 1024 + nn * 8 + j] = f2bf(W1[k * 128 + nn]);
}

// ---------------- GEMM1 (MFMA, resident-B): X[M,256]f32 @ W1 -> h1s bf16, *dinv -----
// W1 (64 KB bf16, kq-major) loaded to LDS once; k-loop barrier-free: per lane
// 2 coalesced float4 A loads from X + cvt + 8 ds_read_b128 + 8 MFMA.
__global__ __launch_bounds__(256) void k_gemm1(const float* __restrict__ X,
                                               const unsigned short* __restrict__ W1t,
                                               const float* __restrict__ dinv,
                                               unsigned short* __restrict__ h1s, int M) {
    __shared__ unsigned short Bs[32768];   // 64 KB, [kq][n][8]
    const int tid = threadIdx.x;
    const int wv = tid >> 6;
    const int lane = tid & 63;
    const int hq = lane >> 4;       // quad 0..3
    const int l15 = lane & 15;
    const int block_row = blockIdx.x * 64;

    // flat 64 KB memcpy global->LDS (uint4 = 16 B per thread per iter)
#pragma unroll
    for (int i = 0; i < 16; ++i)
        ((uint4*)Bs)[tid + i * 256] = ((const uint4*)W1t)[tid + i * 256];
    __syncthreads();

    int arow = block_row + wv * 16 + l15;
    if (arow >= M) arow = M - 1;                       // clamp; stores masked
    const float* xp = X + (size_t)arow * 256 + hq * 8;

    f32x4 acc[8];
#pragma unroll
    for (int c = 0; c < 8; ++c) acc[c] = (f32x4){0.f, 0.f, 0.f, 0.f};

#pragma unroll
    for (int ks = 0; ks < 8; ++ks) {                   // k0 = 32*ks
        float4 a0 = *(const float4*)(xp + 32 * ks);
        float4 a1 = *(const float4*)(xp + 32 * ks + 4);
        short8 a;
        a[0] = (short)f2bf(a0.x); a[1] = (short)f2bf(a0.y);
        a[2] = (short)f2bf(a0.z); a[3] = (short)f2bf(a0.w);
        a[4] = (short)f2bf(a1.x); a[5] = (short)f2bf(a1.y);
        a[6] = (short)f2bf(a1.z); a[7] = (short)f2bf(a1.w);
        const unsigned short* bp = Bs + (ks * 4 + hq) * 1024 + l15 * 8;
#pragma unroll
        for (int c = 0; c < 8; ++c) {
            short8 b = *(const short8*)(bp + c * 128);
            acc[c] = __builtin_amdgcn_mfma_f32_16x16x32_bf16(a, b, acc[c], 0, 0, 0);
        }
    }
    // D: row = 16wv + hq*4 + r, col = c*16 + l15
#pragma unroll
    for (int r = 0; r < 4; ++r) {
        int row = block_row + 16 * wv + hq * 4 + r;
        if (row < M) {
            float dv = dinv[row];
#pragma unroll
            for (int c = 0; c < 8; ++c) {
                int col = c * 16 + l15;
                h1s[(size_t)row * 128 + col] = f2bf(acc[c][r] * dv);
            }
        }
    }
}

// ---------------- agg1: TWO nodes per wave (32 lanes x uint2 = 256B row) -------------
// R14: 8-edge-deep unroll (was 4) -- 8 gathers in flight per wave to close the
// latency-exposure gap (64us at only 2.9 TB/s read). Same layout, same streams.
__global__ __launch_bounds__(256) void k_agg1(const unsigned short* __restrict__ h1s,
                                              const int* __restrict__ rp,
                                              const int* __restrict__ csr,
                                              const float* __restrict__ dinv,
                                              const float* __restrict__ b1,
                                              unsigned short* __restrict__ tbuf, int n) {
    int pr = (blockIdx.x * 256 + threadIdx.x) >> 6;  // wave id = node pair
    int lane = threadIdx.x & 63;
    int half = lane >> 5;
    int l = lane & 31;
    int node = pr * 2 + half;
    if (node >= n) return;
    const uint2* hv = (const uint2*)h1s;  // 32 uint2 per 128-feat row
    uint2 us = hv[((unsigned)node << 5) + l];  // self (already *dinv)
    float a0 = bf2f((unsigned short)(us.x & 0xffff));
    float a1 = bf2f((unsigned short)(us.x >> 16));
    float a2 = bf2f((unsigned short)(us.y & 0xffff));
    float a3 = bf2f((unsigned short)(us.y >> 16));
    int start = rp[node], end = rp[node + 1];
    int e = start;
    for (; e + 8 <= end; e += 8) {
        uint2 u0 = hv[((unsigned)csr[e + 0] << 5) + l];
        uint2 u1 = hv[((unsigned)csr[e + 1] << 5) + l];
        uint2 u2 = hv[((unsigned)csr[e + 2] << 5) + l];
        uint2 u3 = hv[((unsigned)csr[e + 3] << 5) + l];
        uint2 u4 = hv[((unsigned)csr[e + 4] << 5) + l];
        uint2 u5 = hv[((unsigned)csr[e + 5] << 5) + l];
        uint2 u6 = hv[((unsigned)csr[e + 6] << 5) + l];
        uint2 u7 = hv[((unsigned)csr[e + 7] << 5) + l];
        a0 += (bf2f((unsigned short)(u0.x & 0xffff)) + bf2f((unsigned short)(u1.x & 0xffff))) +
              (bf2f((unsigned short)(u2.x & 0xffff)) + bf2f((unsigned short)(u3.x & 0xffff))) +
              (bf2f((unsigned short)(u4.x & 0xffff)) + bf2f((unsigned short)(u5.x & 0xffff))) +
              (bf2f((unsigned short)(u6.x & 0xffff)) + bf2f((unsigned short)(u7.x & 0xffff)));
        a1 += (bf2f((unsigned short)(u0.x >> 16)) + bf2f((unsigned short)(u1.x >> 16))) +
              (bf2f((unsigned short)(u2.x >> 16)) + bf2f((unsigned short)(u3.x >> 16))) +
              (bf2f((unsigned short)(u4.x >> 16)) + bf2f((unsigned short)(u5.x >> 16))) +
              (bf2f((unsigned short)(u6.x >> 16)) + bf2f((unsigned short)(u7.x >> 16)));
        a2 += (bf2f((unsigned short)(u0.y & 0xffff)) + bf2f((unsigned short)(u1.y & 0xffff))) +
              (bf2f((unsigned short)(u2.y & 0xffff)) + bf2f((unsigned short)(u3.y & 0xffff))) +
              (bf2f((unsigned short)(u4.y & 0xffff)) + bf2f((unsigned short)(u5.y & 0xffff))) +
              (bf2f((unsigned short)(u6.y & 0xffff)) + bf2f((unsigned short)(u7.y & 0xffff)));
        a3 += (bf2f((unsigned short)(u0.y >> 16)) + bf2f((unsigned short)(u1.y >> 16))) +
              (bf2f((unsigned short)(u2.y >> 16)) + bf2f((unsigned short)(u3.y >> 16))) +
              (bf2f((unsigned short)(u4.y >> 16)) + bf2f((unsigned short)(u5.y >> 16))) +
              (bf2f((unsigned short)(u6.y >> 16)) + bf2f((unsigned short)(u7.y >> 16)));
    }
    for (; e + 4 <= end; e += 4) {
        uint2 u0 = hv[((unsigned)csr[e + 0] << 5) + l];
        uint2 u1 = hv[((unsigned)csr[e + 1] << 5) + l];
        uint2 u2 = hv[((unsigned)csr[e + 2] << 5) + l];
        uint2 u3 = hv[((unsigned)csr[e + 3] << 5) + l];
        a0 += (bf2f((unsigned short)(u0.x & 0xffff)) + bf2f((unsigned short)(u1.x & 0xffff))) +
              (bf2f((unsigned short)(u2.x & 0xffff)) + bf2f((unsigned short)(u3.x & 0xffff)));
        a1 += (bf2f((unsigned short)(u0.x >> 16)) + bf2f((unsigned short)(u1.x >> 16))) +
              (bf2f((unsigned short)(u2.x >> 16)) + bf2f((unsigned short)(u3.x >> 16)));
        a2 += (bf2f((unsigned short)(u0.y & 0xffff)) + bf2f((unsigned short)(u1.y & 0xffff))) +
              (bf2f((unsigned short)(u2.y & 0xffff)) + bf2f((unsigned short)(u3.y & 0xffff)));
        a3 += (bf2f((unsigned short)(u0.y >> 16)) + bf2f((unsigned short)(u1.y >> 16))) +
              (bf2f((unsigned short)(u2.y >> 16)) + bf2f((unsigned short)(u3.y >> 16)));
    }
    for (; e < end; ++e) {
        uint2 u = hv[((unsigned)csr[e] << 5) + l];
        a0 += bf2f((unsigned short)(u.x & 0xffff));
        a1 += bf2f((unsigned short)(u.x >> 16));
        a2 += bf2f((unsigned short)(u.y & 0xffff));
        a3 += bf2f((unsigned short)(u.y >> 16));
    }
    float dv = dinv[node];
    float4 bb = ((const float4*)b1)[l];
    float t0 = fmaxf(dv * a0 + bb.x, 0.0f);
    float t1 = fmaxf(dv * a1 + bb.y, 0.0f);
    float t2 = fmaxf(dv * a2 + bb.z, 0.0f);
    float t3 = fmaxf(dv * a3 + bb.w, 0.0f);
    uint2 packed;
    packed.x = (unsigned int)f2bf(t0) | ((unsigned int)f2bf(t1) << 16);
    packed.y = (unsigned int)f2bf(t2) | ((unsigned int)f2bf(t3) << 16);
    ((uint2*)tbuf)[((unsigned)node << 5) + l] = packed;
}

// ---------------- GEMM2: tbuf[n,128]bf16 @ W2[128,16]f32 -> h2s bf16, *dinv ----------
__global__ __launch_bounds__(256) void k_gemm2(const unsigned short* __restrict__ tbuf,
                                               const float* __restrict__ W2,
                                               const float* __restrict__ dinv,
                                               unsigned short* __restrict__ h2s, int n) {
    __shared__ float w2s[128 * 16];
    for (int i = threadIdx.x; i < 2048; i += 256) w2s[i] = W2[i];
    __syncthreads();
    int gid = blockIdx.x * 256 + threadIdx.x;
    int node = gid >> 4;
    int o = gid & 15;
    if (node >= n) return;
    const uint4* tv = (const uint4*)(tbuf + (size_t)node * 128);  // 16 x uint4
    float acc = 0.0f;
#pragma unroll
    for (int i = 0; i < 16; ++i) {
        uint4 u = tv[i];
        int k = i * 8;
        acc += __uint_as_float(u.x << 16) * w2s[(k + 0) * 16 + o];
        acc += __uint_as_float(u.x & 0xffff0000u) * w2s[(k + 1) * 16 + o];
        acc += __uint_as_float(u.y << 16) * w2s[(k + 2) * 16 + o];
        acc += __uint_as_float(u.y & 0xffff0000u) * w2s[(k + 3) * 16 + o];
        acc += __uint_as_float(u.z << 16) * w2s[(k + 4) * 16 + o];
        acc += __uint_as_float(u.z & 0xffff0000u) * w2s[(k + 5) * 16 + o];
        acc += __uint_as_float(u.w << 16) * w2s[(k + 6) * 16 + o];
        acc += __uint_as_float(u.w & 0xffff0000u) * w2s[(k + 7) * 16 + o];
    }
    h2s[(size_t)node * 16 + o] = f2bf(acc * dinv[node]);
}

// ---------------- agg2: 4 lanes/node, uint2 (4 bf16 feats) per lane ----------------
__global__ __launch_bounds__(256) void k_agg2(const unsigned short* __restrict__ h2s,
                                              const int* __restrict__ rp,
                                              const int* __restrict__ csr,
                                              const float* __restrict__ dinv,
                                              const float* __restrict__ b2,
                                              float* __restrict__ out, int n) {
    int wid = (blockIdx.x * 256 + threadIdx.x) >> 6;
    int lane = threadIdx.x & 63;
    int slot = lane >> 2;
    int q = lane & 3;
    int node = wid * 16 + slot;
    bool valid = node < n;
    int nodec = valid ? node : n - 1;
    int start = rp[nodec];
    int deg = rp[nodec + 1] - start;
    int mx = deg;
#pragma unroll
    for (int off = 4; off < 64; off <<= 1) mx = max(mx, __shfl_xor(mx, off));
    uint2 us = *(const uint2*)(h2s + ((unsigned)nodec << 4) + q * 4);
    float a0 = bf2f((unsigned short)(us.x & 0xffff));
    float a1 = bf2f((unsigned short)(us.x >> 16));
    float a2 = bf2f((unsigned short)(us.y & 0xffff));
    float a3 = bf2f((unsigned short)(us.y >> 16));
    int clampi = deg > 0 ? deg - 1 : 0;
    int e = 0;
    for (; e + 2 <= mx; e += 2) {
        int s0 = csr[start + min(e, clampi)];
        int s1 = csr[start + min(e + 1, clampi)];
        uint2 u0 = *(const uint2*)(h2s + ((unsigned)s0 << 4) + q * 4);
        uint2 u1 = *(const uint2*)(h2s + ((unsigned)s1 << 4) + q * 4);
        if (e < deg) {
            a0 += bf2f((unsigned short)(u0.x & 0xffff));
            a1 += bf2f((unsigned short)(u0.x >> 16));
            a2 += bf2f((unsigned short)(u0.y & 0xffff));
            a3 += bf2f((unsigned short)(u0.y >> 16));
        }
        if (e + 1 < deg) {
            a0 += bf2f((unsigned short)(u1.x & 0xffff));
            a1 += bf2f((unsigned short)(u1.x >> 16));
            a2 += bf2f((unsigned short)(u1.y & 0xffff));
            a3 += bf2f((unsigned short)(u1.y >> 16));
        }
    }
    if (e < mx && e < deg) {
        int s = csr[start + e];
        uint2 u = *(const uint2*)(h2s + ((unsigned)s << 4) + q * 4);
        a0 += bf2f((unsigned short)(u.x & 0xffff));
        a1 += bf2f((unsigned short)(u.x >> 16));
        a2 += bf2f((unsigned short)(u.y & 0xffff));
        a3 += bf2f((unsigned short)(u.y >> 16));
    }
    if (valid) {
        float dv = dinv[node];
        float4 bb = *(const float4*)(b2 + q * 4);
        float4 o4 = make_float4(dv * a0 + bb.x, dv * a1 + bb.y,
                                dv * a2 + bb.z, dv * a3 + bb.w);
        *(float4*)(out + ((unsigned)node << 4) + q * 4) = o4;
    }
}

extern "C" void kernel_launch(void* const* d_in, const int* in_sizes, int n_in,
                              void* d_out, int out_size, void* d_ws, size_t ws_size,
                              hipStream_t stream) {
    const float* X  = (const float*)d_in[0];
    const int*   ei = (const int*)d_in[1];
    const float* W1 = (const float*)d_in[2];
    const float* b1 = (const float*)d_in[3];
    const float* W2 = (const float*)d_in[4];
    const float* b2 = (const float*)d_in[5];
    float* out = (float*)d_out;

    const int n = in_sizes[0] / N_FEAT_IN;   // 100000
    const int E = in_sizes[1] / 2;           // 1600000
    const int* src = ei;
    const int* dst = ei + E;

    char* ws = (char*)d_ws;
    size_t off = 0;
    auto alloc = [&](size_t bytes) -> char* {
        char* p = ws + off;
        off = (off + bytes + 255) & ~(size_t)255;
        return p;
    };
    float*          dinv    = (float*)alloc((size_t)n * 4);
    int*            row_ptr = (int*)alloc((size_t)(n + 1) * 4);
    int*            bbc     = (int*)alloc((size_t)NBUCK * NBINBLK * 4);  // 1 MB
    int*            btot    = (int*)alloc(NBUCK * 4);
    int*            bbase   = (int*)alloc((NBUCK + 1) * 4);
    int*            csr     = (int*)alloc((size_t)E * 4);
    int*            ebuf    = (int*)alloc((size_t)E * 4);                // 6.4 MB packed
    unsigned short* W1t     = (unsigned short*)alloc(128 * 256 * 2);     // 64 KB packed
    unsigned short* h1s     = (unsigned short*)alloc((size_t)n * 128 * 2);
    unsigned short* tbuf    = (unsigned short*)alloc((size_t)n * 128 * 2);
    unsigned short* h2s     = (unsigned short*)alloc((size_t)n * 16 * 2);
    (void)ws_size;

    const int NBK = (n + 127) / 128;         // 782 used buckets
    const int chunk = (E + NBINBLK - 1) / NBINBLK;

    k_bhist<<<NBINBLK, 256, 0, stream>>>(dst, bbc, E, chunk);
    k_bexscan<<<NBUCK, 256, 0, stream>>>(bbc, btot);
    k_bscan<<<1, NBUCK, 0, stream>>>(btot, bbase);
    k_bin2<<<NBINBLK, 256, 0, stream>>>(src, dst, bbc, bbase, ebuf, E, chunk);
    k_sortb<<<NBK, 256, 0, stream>>>(ebuf, bbase, row_ptr, dinv, csr, n, E);

    k_prep<<<128, 256, 0, stream>>>(W1, W1t);
    k_gemm1<<<(n + 63) / 64, 256, 0, stream>>>(X, W1t, dinv, h1s, n);
    k_agg1<<<(n / 2 + 3) / 4, 256, 0, stream>>>(h1s, row_ptr, csr, dinv, b1, tbuf, n);
    k_gemm2<<<((size_t)n * 16 + 255) / 256, 256, 0, stream>>>(tbuf, W2, dinv, h2s, n);
    k_agg2<<<(n + 63) / 64, 256, 0, stream>>>(h2s, row_ptr, csr, dinv, b2, out, n);
}

// Round 7
// 335.237 us; speedup vs baseline: 1.2172x; 1.0243x over previous
//
#include <hip/hip_runtime.h>
#include <hip/hip_bf16.h>

// SocialGNN: 2-layer GCN, N=100000 nodes, E=1600000 edges (+ self loops),
// feat 256 -> 128 (relu) -> 16.
//
// R16 = R15 with the nontemporal builtins fixed: __builtin_nontemporal_*
// requires clang ext_vector types, not HIP_vector_type structs (R15 compile
// fail). Changes vs R14 baseline (343us):
//  (a) gemm1: half-K staging (32 KB LDS, 2 phases, 3 barriers/block) lifts
//      occupancy 2->5 blocks/CU for the 102MB X stream; X loads non-temporal.
//  (b) agg2: per-group divergent edge loop (drops the uniform-mx clamped
//      dummy loads, ~38% wasted gather requests) + 8-deep unroll; nt out.
//  (c) read-once streams nt: tbuf store (agg1), tbuf load (gemm2).
// History: R2 -- never funnel E atomics into <1K addresses. R4 -- bf16
// intermediates halve gather traffic. R7 -- per-wave-redundant MFMA operand
// streams from global = 2x regression. R9 -- resident-B LDS gemm1. R10-R13 --
// XCD feature-chunking branch abandoned (floor merely matches row-major 64us;
// node reordering poisons store coalescing). R14 -- 8-deep agg1: 64->61us,
// traffic unchanged; agg1 at random-access HBM roofline (~3.6 TB/s, 218MB).

typedef __attribute__((ext_vector_type(8))) short short8;
typedef __attribute__((ext_vector_type(4))) float f32x4;
typedef __attribute__((ext_vector_type(2))) unsigned int u32x2;
typedef __attribute__((ext_vector_type(4))) unsigned int u32x4;

__device__ inline unsigned short f2bf(float f) {
    __hip_bfloat16 h = __float2bfloat16(f);
    return *(unsigned short*)&h;
}
__device__ inline float bf2f(unsigned short u) {
    unsigned int v = ((unsigned int)u) << 16;
    return *(float*)&v;
}

#define N_FEAT_IN 256
#define NBUCK 1024     // dst>>7; used buckets = ceil(n/128) = 782
#define NBINBLK 256    // partition blocks; bbc is [NBUCK][NBINBLK]

// ---------------- partition pass 1: per-(block,bucket) LDS histogram ----------------
__global__ __launch_bounds__(256) void k_bhist(const int* __restrict__ dst,
                                               int* __restrict__ bbc, int E, int chunk) {
    __shared__ int lcnt[NBUCK];
    for (int i = threadIdx.x; i < NBUCK; i += 256) lcnt[i] = 0;
    __syncthreads();
    int start = blockIdx.x * chunk;
    int end = min(start + chunk, E);
    for (int e = start + threadIdx.x; e < end; e += 256)
        atomicAdd(&lcnt[dst[e] >> 7], 1);
    __syncthreads();
    for (int i = threadIdx.x; i < NBUCK; i += 256)
        bbc[i * NBINBLK + blockIdx.x] = lcnt[i];
}

// ---- partition pass 2: per-bucket local exclusive scan across blocks + totals ----
__global__ __launch_bounds__(256) void k_bexscan(int* __restrict__ bbc,
                                                 int* __restrict__ btot) {
    __shared__ int ts[NBINBLK];
    int bucket = blockIdx.x;
    int t = threadIdx.x;
    int v = bbc[bucket * NBINBLK + t];
    ts[t] = v; __syncthreads();
    for (int off = 1; off < NBINBLK; off <<= 1) {
        int x = (t >= off) ? ts[t - off] : 0;
        __syncthreads();
        ts[t] += x;
        __syncthreads();
    }
    bbc[bucket * NBINBLK + t] = ts[t] - v;   // local exclusive (no base yet)
    if (t == NBINBLK - 1) btot[bucket] = ts[t];
}

// ---------------- bucket-total exclusive scan -> bucket bases ----------------
__global__ __launch_bounds__(1024) void k_bscan(const int* __restrict__ btot,
                                                int* __restrict__ bbase) {
    __shared__ int ts[NBUCK];
    int t = threadIdx.x;
    int v = btot[t];
    ts[t] = v; __syncthreads();
    for (int off = 1; off < NBUCK; off <<= 1) {
        int x = (t >= off) ? ts[t - off] : 0;
        __syncthreads();
        ts[t] += x;
        __syncthreads();
    }
    bbase[t] = ts[t] - v;  // exclusive
}

// ---------------- partition pass 3: binned write (24-bit packed) ----------------
// packed edge: bits 0-16 src (n<2^17), bits 17-23 dst&127.
__global__ __launch_bounds__(256) void k_bin2(const int* __restrict__ src,
                                              const int* __restrict__ dst,
                                              const int* __restrict__ bbc,
                                              const int* __restrict__ bbase,
                                              int* __restrict__ ebuf, int E, int chunk) {
    __shared__ int lcur[NBUCK];
    for (int i = threadIdx.x; i < NBUCK; i += 256)
        lcur[i] = bbc[i * NBINBLK + blockIdx.x] + bbase[i];
    __syncthreads();
    int start = blockIdx.x * chunk;
    int end = min(start + chunk, E);
    for (int e = start + threadIdx.x; e < end; e += 256) {
        int s = src[e], d = dst[e];
        int pos = atomicAdd(&lcur[d >> 7], 1);  // LDS atomic
        ebuf[pos] = s | ((d & 127) << 17);
    }
}

// ---- per-bucket counting sort: ebuf window -> csr; also row_ptr, dinv ----
__global__ __launch_bounds__(256) void k_sortb(const int* __restrict__ ebuf,
                                               const int* __restrict__ bbase,
                                               int* __restrict__ row_ptr,
                                               float* __restrict__ dinv,
                                               int* __restrict__ csr, int n, int E) {
    __shared__ int lcnt[128];
    __shared__ int lcur[128];
    int b = blockIdx.x;
    int node0 = b << 7;
    int nodes = min(128, n - node0);
    int t = threadIdx.x;
    int s_start = bbase[b];
    int s_end = bbase[b + 1];
    if (t < 128) lcnt[t] = 0;
    __syncthreads();
    for (int e = s_start + t; e < s_end; e += 256)
        atomicAdd(&lcnt[(ebuf[e] >> 17) & 127], 1);
    __syncthreads();
    int deg = (t < 128) ? lcnt[t] : 0;
    if (t < 128) lcur[t] = deg;
    __syncthreads();
    for (int off = 1; off < 128; off <<= 1) {
        int x = 0;
        if (t < 128 && t >= off) x = lcur[t - off];
        __syncthreads();
        if (t < 128) lcur[t] += x;
        __syncthreads();
    }
    if (t < 128) {
        int excl = s_start + lcur[t] - deg;
        if (t < nodes) {
            row_ptr[node0 + t] = excl;
            dinv[node0 + t] = rsqrtf((float)deg + 1.0f);  // +1 self-loop
        }
        lcur[t] = excl;  // write cursor
    }
    if (b == 0 && t == 0) row_ptr[n] = E;
    __syncthreads();
    for (int e = s_start + t; e < s_end; e += 256) {
        int p = ebuf[e];
        int pos = atomicAdd(&lcur[(p >> 17) & 127], 1);  // LDS atomic
        csr[pos] = p & 0x1FFFF;
    }
}

// ------ W1 [256][128] f32 -> W1t packed [kq 0..31][n 0..127][j 0..7] bf16 ------
// element (n, k=kq*8+j) lives at W1t[kq*1024 + n*8 + j].
__global__ void k_prep(const float* __restrict__ W1, unsigned short* __restrict__ W1t) {
    int nn = blockIdx.x;          // 0..127
    int k = threadIdx.x;          // 0..255
    int kq = k >> 3, j = k & 7;
    W1t[kq * 1024 + nn * 8 + j] = f2bf(W1[k * 128 + nn]);
}

// ---------------- GEMM1 (MFMA, half-K resident-B): X[M,256]f32 @ W1 -> h1s ----------
// 32 KB LDS (half of W1 at a time, kq 0..15 then 16..31), 2 compute phases,
// 3 barriers/block -> 5 blocks/CU (was 2 with 64 KB). X loads non-temporal.
__global__ __launch_bounds__(256) void k_gemm1(const float* __restrict__ X,
                                               const unsigned short* __restrict__ W1t,
                                               const float* __restrict__ dinv,
                                               unsigned short* __restrict__ h1s, int M) {
    __shared__ unsigned short Bs[16384];   // 32 KB, [kq' 0..15][n][8]
    const int tid = threadIdx.x;
    const int wv = tid >> 6;
    const int lane = tid & 63;
    const int hq = lane >> 4;       // quad 0..3
    const int l15 = lane & 15;
    const int block_row = blockIdx.x * 64;

    int arow = block_row + wv * 16 + l15;
    if (arow >= M) arow = M - 1;                       // clamp; stores masked
    const float* xp = X + (size_t)arow * 256 + hq * 8;

    f32x4 acc[8];
#pragma unroll
    for (int c = 0; c < 8; ++c) acc[c] = (f32x4){0.f, 0.f, 0.f, 0.f};

#pragma unroll
    for (int ph = 0; ph < 2; ++ph) {
        if (ph) __syncthreads();           // all reads of phase 0 done
        // fill 32 KB: 8 x uint4 per thread (kq ph*16 .. ph*16+15)
#pragma unroll
        for (int i = 0; i < 8; ++i)
            ((u32x4*)Bs)[tid + i * 256] = ((const u32x4*)W1t)[ph * 2048 + tid + i * 256];
        __syncthreads();
#pragma unroll
        for (int ks4 = 0; ks4 < 4; ++ks4) {            // ks = ph*4 + ks4
            const int ks = ph * 4 + ks4;
            f32x4 a0 = __builtin_nontemporal_load((const f32x4*)(xp + 32 * ks));
            f32x4 a1 = __builtin_nontemporal_load((const f32x4*)(xp + 32 * ks + 4));
            short8 a;
            a[0] = (short)f2bf(a0[0]); a[1] = (short)f2bf(a0[1]);
            a[2] = (short)f2bf(a0[2]); a[3] = (short)f2bf(a0[3]);
            a[4] = (short)f2bf(a1[0]); a[5] = (short)f2bf(a1[1]);
            a[6] = (short)f2bf(a1[2]); a[7] = (short)f2bf(a1[3]);
            const unsigned short* bp = Bs + (ks4 * 4 + hq) * 1024 + l15 * 8;
#pragma unroll
            for (int c = 0; c < 8; ++c) {
                short8 b = *(const short8*)(bp + c * 128);
                acc[c] = __builtin_amdgcn_mfma_f32_16x16x32_bf16(a, b, acc[c], 0, 0, 0);
            }
        }
    }
    // D: row = 16wv + hq*4 + r, col = c*16 + l15
#pragma unroll
    for (int r = 0; r < 4; ++r) {
        int row = block_row + 16 * wv + hq * 4 + r;
        if (row < M) {
            float dv = dinv[row];
#pragma unroll
            for (int c = 0; c < 8; ++c) {
                int col = c * 16 + l15;
                h1s[(size_t)row * 128 + col] = f2bf(acc[c][r] * dv);
            }
        }
    }
}

// ---------------- agg1: TWO nodes per wave (32 lanes x uint2 = 256B row) -------------
// R14 structure (proven 61us, 188MB fetch). tbuf store non-temporal only.
__global__ __launch_bounds__(256) void k_agg1(const unsigned short* __restrict__ h1s,
                                              const int* __restrict__ rp,
                                              const int* __restrict__ csr,
                                              const float* __restrict__ dinv,
                                              const float* __restrict__ b1,
                                              unsigned short* __restrict__ tbuf, int n) {
    int pr = (blockIdx.x * 256 + threadIdx.x) >> 6;  // wave id = node pair
    int lane = threadIdx.x & 63;
    int half = lane >> 5;
    int l = lane & 31;
    int node = pr * 2 + half;
    if (node >= n) return;
    const uint2* hv = (const uint2*)h1s;  // 32 uint2 per 128-feat row
    uint2 us = hv[((unsigned)node << 5) + l];  // self (already *dinv)
    float a0 = bf2f((unsigned short)(us.x & 0xffff));
    float a1 = bf2f((unsigned short)(us.x >> 16));
    float a2 = bf2f((unsigned short)(us.y & 0xffff));
    float a3 = bf2f((unsigned short)(us.y >> 16));
    int start = rp[node], end = rp[node + 1];
    int e = start;
    for (; e + 8 <= end; e += 8) {
        uint2 u0 = hv[((unsigned)csr[e + 0] << 5) + l];
        uint2 u1 = hv[((unsigned)csr[e + 1] << 5) + l];
        uint2 u2 = hv[((unsigned)csr[e + 2] << 5) + l];
        uint2 u3 = hv[((unsigned)csr[e + 3] << 5) + l];
        uint2 u4 = hv[((unsigned)csr[e + 4] << 5) + l];
        uint2 u5 = hv[((unsigned)csr[e + 5] << 5) + l];
        uint2 u6 = hv[((unsigned)csr[e + 6] << 5) + l];
        uint2 u7 = hv[((unsigned)csr[e + 7] << 5) + l];
        a0 += (bf2f((unsigned short)(u0.x & 0xffff)) + bf2f((unsigned short)(u1.x & 0xffff))) +
              (bf2f((unsigned short)(u2.x & 0xffff)) + bf2f((unsigned short)(u3.x & 0xffff))) +
              (bf2f((unsigned short)(u4.x & 0xffff)) + bf2f((unsigned short)(u5.x & 0xffff))) +
              (bf2f((unsigned short)(u6.x & 0xffff)) + bf2f((unsigned short)(u7.x & 0xffff)));
        a1 += (bf2f((unsigned short)(u0.x >> 16)) + bf2f((unsigned short)(u1.x >> 16))) +
              (bf2f((unsigned short)(u2.x >> 16)) + bf2f((unsigned short)(u3.x >> 16))) +
              (bf2f((unsigned short)(u4.x >> 16)) + bf2f((unsigned short)(u5.x >> 16))) +
              (bf2f((unsigned short)(u6.x >> 16)) + bf2f((unsigned short)(u7.x >> 16)));
        a2 += (bf2f((unsigned short)(u0.y & 0xffff)) + bf2f((unsigned short)(u1.y & 0xffff))) +
              (bf2f((unsigned short)(u2.y & 0xffff)) + bf2f((unsigned short)(u3.y & 0xffff))) +
              (bf2f((unsigned short)(u4.y & 0xffff)) + bf2f((unsigned short)(u5.y & 0xffff))) +
              (bf2f((unsigned short)(u6.y & 0xffff)) + bf2f((unsigned short)(u7.y & 0xffff)));
        a3 += (bf2f((unsigned short)(u0.y >> 16)) + bf2f((unsigned short)(u1.y >> 16))) +
              (bf2f((unsigned short)(u2.y >> 16)) + bf2f((unsigned short)(u3.y >> 16))) +
              (bf2f((unsigned short)(u4.y >> 16)) + bf2f((unsigned short)(u5.y >> 16))) +
              (bf2f((unsigned short)(u6.y >> 16)) + bf2f((unsigned short)(u7.y >> 16)));
    }
    for (; e + 4 <= end; e += 4) {
        uint2 u0 = hv[((unsigned)csr[e + 0] << 5) + l];
        uint2 u1 = hv[((unsigned)csr[e + 1] << 5) + l];
        uint2 u2 = hv[((unsigned)csr[e + 2] << 5) + l];
        uint2 u3 = hv[((unsigned)csr[e + 3] << 5) + l];
        a0 += (bf2f((unsigned short)(u0.x & 0xffff)) + bf2f((unsigned short)(u1.x & 0xffff))) +
              (bf2f((unsigned short)(u2.x & 0xffff)) + bf2f((unsigned short)(u3.x & 0xffff)));
        a1 += (bf2f((unsigned short)(u0.x >> 16)) + bf2f((unsigned short)(u1.x >> 16))) +
              (bf2f((unsigned short)(u2.x >> 16)) + bf2f((unsigned short)(u3.x >> 16)));
        a2 += (bf2f((unsigned short)(u0.y & 0xffff)) + bf2f((unsigned short)(u1.y & 0xffff))) +
              (bf2f((unsigned short)(u2.y & 0xffff)) + bf2f((unsigned short)(u3.y & 0xffff)));
        a3 += (bf2f((unsigned short)(u0.y >> 16)) + bf2f((unsigned short)(u1.y >> 16))) +
              (bf2f((unsigned short)(u2.y >> 16)) + bf2f((unsigned short)(u3.y >> 16)));
    }
    for (; e < end; ++e) {
        uint2 u = hv[((unsigned)csr[e] << 5) + l];
        a0 += bf2f((unsigned short)(u.x & 0xffff));
        a1 += bf2f((unsigned short)(u.x >> 16));
        a2 += bf2f((unsigned short)(u.y & 0xffff));
        a3 += bf2f((unsigned short)(u.y >> 16));
    }
    float dv = dinv[node];
    float4 bb = ((const float4*)b1)[l];
    float t0 = fmaxf(dv * a0 + bb.x, 0.0f);
    float t1 = fmaxf(dv * a1 + bb.y, 0.0f);
    float t2 = fmaxf(dv * a2 + bb.z, 0.0f);
    float t3 = fmaxf(dv * a3 + bb.w, 0.0f);
    u32x2 packed;
    packed[0] = (unsigned int)f2bf(t0) | ((unsigned int)f2bf(t1) << 16);
    packed[1] = (unsigned int)f2bf(t2) | ((unsigned int)f2bf(t3) << 16);
    __builtin_nontemporal_store(packed, (u32x2*)tbuf + (((unsigned)node << 5) + l));
}

// ---------------- GEMM2: tbuf[n,128]bf16 @ W2[128,16]f32 -> h2s bf16, *dinv ----------
// tbuf loads non-temporal (read-once; keep L2 for h2s gather table).
__global__ __launch_bounds__(256) void k_gemm2(const unsigned short* __restrict__ tbuf,
                                               const float* __restrict__ W2,
                                               const float* __restrict__ dinv,
                                               unsigned short* __restrict__ h2s, int n) {
    __shared__ float w2s[128 * 16];
    for (int i = threadIdx.x; i < 2048; i += 256) w2s[i] = W2[i];
    __syncthreads();
    int gid = blockIdx.x * 256 + threadIdx.x;
    int node = gid >> 4;
    int o = gid & 15;
    if (node >= n) return;
    const u32x4* tv = (const u32x4*)(tbuf + (size_t)node * 128);  // 16 x 16B
    float acc = 0.0f;
#pragma unroll
    for (int i = 0; i < 16; ++i) {
        u32x4 u = __builtin_nontemporal_load(tv + i);
        int k = i * 8;
        acc += __uint_as_float(u[0] << 16) * w2s[(k + 0) * 16 + o];
        acc += __uint_as_float(u[0] & 0xffff0000u) * w2s[(k + 1) * 16 + o];
        acc += __uint_as_float(u[1] << 16) * w2s[(k + 2) * 16 + o];
        acc += __uint_as_float(u[1] & 0xffff0000u) * w2s[(k + 3) * 16 + o];
        acc += __uint_as_float(u[2] << 16) * w2s[(k + 4) * 16 + o];
        acc += __uint_as_float(u[2] & 0xffff0000u) * w2s[(k + 5) * 16 + o];
        acc += __uint_as_float(u[3] << 16) * w2s[(k + 6) * 16 + o];
        acc += __uint_as_float(u[3] & 0xffff0000u) * w2s[(k + 7) * 16 + o];
    }
    h2s[(size_t)node * 16 + o] = f2bf(acc * dinv[node]);
}

// ---------------- agg2 (R16): 4 lanes/node, per-group divergent loop, 8-deep --------
// h2s table is 3.2 MB (fits per-XCD L2): gathers are L2 hits; the old
// uniform-mx loop issued ~38% clamped dummy loads with only 2 in flight.
// Each 4-lane group iterates its own degree (exec-masked), 8 gathers in
// flight; no wasted requests. out store non-temporal.
__global__ __launch_bounds__(256) void k_agg2(const unsigned short* __restrict__ h2s,
                                              const int* __restrict__ rp,
                                              const int* __restrict__ csr,
                                              const float* __restrict__ dinv,
                                              const float* __restrict__ b2,
                                              float* __restrict__ out, int n) {
    int wid = (blockIdx.x * 256 + threadIdx.x) >> 6;
    int lane = threadIdx.x & 63;
    int slot = lane >> 2;
    int q = lane & 3;
    int node = wid * 16 + slot;
    if (node >= n) return;
    uint2 us = *(const uint2*)(h2s + ((unsigned)node << 4) + q * 4);
    float a0 = bf2f((unsigned short)(us.x & 0xffff));
    float a1 = bf2f((unsigned short)(us.x >> 16));
    float a2 = bf2f((unsigned short)(us.y & 0xffff));
    float a3 = bf2f((unsigned short)(us.y >> 16));
    int e = rp[node];
    const int end = rp[node + 1];
    for (; e + 8 <= end; e += 8) {
        int s0 = csr[e + 0], s1 = csr[e + 1], s2 = csr[e + 2], s3 = csr[e + 3];
        int s4 = csr[e + 4], s5 = csr[e + 5], s6 = csr[e + 6], s7 = csr[e + 7];
        uint2 u0 = *(const uint2*)(h2s + ((unsigned)s0 << 4) + q * 4);
        uint2 u1 = *(const uint2*)(h2s + ((unsigned)s1 << 4) + q * 4);
        uint2 u2 = *(const uint2*)(h2s + ((unsigned)s2 << 4) + q * 4);
        uint2 u3 = *(const uint2*)(h2s + ((unsigned)s3 << 4) + q * 4);
        uint2 u4 = *(const uint2*)(h2s + ((unsigned)s4 << 4) + q * 4);
        uint2 u5 = *(const uint2*)(h2s + ((unsigned)s5 << 4) + q * 4);
        uint2 u6 = *(const uint2*)(h2s + ((unsigned)s6 << 4) + q * 4);
        uint2 u7 = *(const uint2*)(h2s + ((unsigned)s7 << 4) + q * 4);
        a0 += (bf2f((unsigned short)(u0.x & 0xffff)) + bf2f((unsigned short)(u1.x & 0xffff))) +
              (bf2f((unsigned short)(u2.x & 0xffff)) + bf2f((unsigned short)(u3.x & 0xffff))) +
              (bf2f((unsigned short)(u4.x & 0xffff)) + bf2f((unsigned short)(u5.x & 0xffff))) +
              (bf2f((unsigned short)(u6.x & 0xffff)) + bf2f((unsigned short)(u7.x & 0xffff)));
        a1 += (bf2f((unsigned short)(u0.x >> 16)) + bf2f((unsigned short)(u1.x >> 16))) +
              (bf2f((unsigned short)(u2.x >> 16)) + bf2f((unsigned short)(u3.x >> 16))) +
              (bf2f((unsigned short)(u4.x >> 16)) + bf2f((unsigned short)(u5.x >> 16))) +
              (bf2f((unsigned short)(u6.x >> 16)) + bf2f((unsigned short)(u7.x >> 16)));
        a2 += (bf2f((unsigned short)(u0.y & 0xffff)) + bf2f((unsigned short)(u1.y & 0xffff))) +
              (bf2f((unsigned short)(u2.y & 0xffff)) + bf2f((unsigned short)(u3.y & 0xffff))) +
              (bf2f((unsigned short)(u4.y & 0xffff)) + bf2f((unsigned short)(u5.y & 0xffff))) +
              (bf2f((unsigned short)(u6.y & 0xffff)) + bf2f((unsigned short)(u7.y & 0xffff)));
        a3 += (bf2f((unsigned short)(u0.y >> 16)) + bf2f((unsigned short)(u1.y >> 16))) +
              (bf2f((unsigned short)(u2.y >> 16)) + bf2f((unsigned short)(u3.y >> 16))) +
              (bf2f((unsigned short)(u4.y >> 16)) + bf2f((unsigned short)(u5.y >> 16))) +
              (bf2f((unsigned short)(u6.y >> 16)) + bf2f((unsigned short)(u7.y >> 16)));
    }
    for (; e + 4 <= end; e += 4) {
        int s0 = csr[e + 0], s1 = csr[e + 1], s2 = csr[e + 2], s3 = csr[e + 3];
        uint2 u0 = *(const uint2*)(h2s + ((unsigned)s0 << 4) + q * 4);
        uint2 u1 = *(const uint2*)(h2s + ((unsigned)s1 << 4) + q * 4);
        uint2 u2 = *(const uint2*)(h2s + ((unsigned)s2 << 4) + q * 4);
        uint2 u3 = *(const uint2*)(h2s + ((unsigned)s3 << 4) + q * 4);
        a0 += (bf2f((unsigned short)(u0.x & 0xffff)) + bf2f((unsigned short)(u1.x & 0xffff))) +
              (bf2f((unsigned short)(u2.x & 0xffff)) + bf2f((unsigned short)(u3.x & 0xffff)));
        a1 += (bf2f((unsigned short)(u0.x >> 16)) + bf2f((unsigned short)(u1.x >> 16))) +
              (bf2f((unsigned short)(u2.x >> 16)) + bf2f((unsigned short)(u3.x >> 16)));
        a2 += (bf2f((unsigned short)(u0.y & 0xffff)) + bf2f((unsigned short)(u1.y & 0xffff))) +
              (bf2f((unsigned short)(u2.y & 0xffff)) + bf2f((unsigned short)(u3.y & 0xffff)));
        a3 += (bf2f((unsigned short)(u0.y >> 16)) + bf2f((unsigned short)(u1.y >> 16))) +
              (bf2f((unsigned short)(u2.y >> 16)) + bf2f((unsigned short)(u3.y >> 16)));
    }
    for (; e < end; ++e) {
        int s = csr[e];
        uint2 u = *(const uint2*)(h2s + ((unsigned)s << 4) + q * 4);
        a0 += bf2f((unsigned short)(u.x & 0xffff));
        a1 += bf2f((unsigned short)(u.x >> 16));
        a2 += bf2f((unsigned short)(u.y & 0xffff));
        a3 += bf2f((unsigned short)(u.y >> 16));
    }
    float dv = dinv[node];
    float4 bb = *(const float4*)(b2 + q * 4);
    f32x4 o4;
    o4[0] = dv * a0 + bb.x;
    o4[1] = dv * a1 + bb.y;
    o4[2] = dv * a2 + bb.z;
    o4[3] = dv * a3 + bb.w;
    __builtin_nontemporal_store(o4, (f32x4*)(out + ((unsigned)node << 4) + q * 4));
}

extern "C" void kernel_launch(void* const* d_in, const int* in_sizes, int n_in,
                              void* d_out, int out_size, void* d_ws, size_t ws_size,
                              hipStream_t stream) {
    const float* X  = (const float*)d_in[0];
    const int*   ei = (const int*)d_in[1];
    const float* W1 = (const float*)d_in[2];
    const float* b1 = (const float*)d_in[3];
    const float* W2 = (const float*)d_in[4];
    const float* b2 = (const float*)d_in[5];
    float* out = (float*)d_out;

    const int n = in_sizes[0] / N_FEAT_IN;   // 100000
    const int E = in_sizes[1] / 2;           // 1600000
    const int* src = ei;
    const int* dst = ei + E;

    char* ws = (char*)d_ws;
    size_t off = 0;
    auto alloc = [&](size_t bytes) -> char* {
        char* p = ws + off;
        off = (off + bytes + 255) & ~(size_t)255;
        return p;
    };
    float*          dinv    = (float*)alloc((size_t)n * 4);
    int*            row_ptr = (int*)alloc((size_t)(n + 1) * 4);
    int*            bbc     = (int*)alloc((size_t)NBUCK * NBINBLK * 4);  // 1 MB
    int*            btot    = (int*)alloc(NBUCK * 4);
    int*            bbase   = (int*)alloc((NBUCK + 1) * 4);
    int*            csr     = (int*)alloc((size_t)E * 4);
    int*            ebuf    = (int*)alloc((size_t)E * 4);                // 6.4 MB packed
    unsigned short* W1t     = (unsigned short*)alloc(128 * 256 * 2);     // 64 KB packed
    unsigned short* h1s     = (unsigned short*)alloc((size_t)n * 128 * 2);
    unsigned short* tbuf    = (unsigned short*)alloc((size_t)n * 128 * 2);
    unsigned short* h2s     = (unsigned short*)alloc((size_t)n * 16 * 2);
    (void)ws_size;

    const int NBK = (n + 127) / 128;         // 782 used buckets
    const int chunk = (E + NBINBLK - 1) / NBINBLK;

    k_bhist<<<NBINBLK, 256, 0, stream>>>(dst, bbc, E, chunk);
    k_bexscan<<<NBUCK, 256, 0, stream>>>(bbc, btot);
    k_bscan<<<1, NBUCK, 0, stream>>>(btot, bbase);
    k_bin2<<<NBINBLK, 256, 0, stream>>>(src, dst, bbc, bbase, ebuf, E, chunk);
    k_sortb<<<NBK, 256, 0, stream>>>(ebuf, bbase, row_ptr, dinv, csr, n, E);

    k_prep<<<128, 256, 0, stream>>>(W1, W1t);
    k_gemm1<<<(n + 63) / 64, 256, 0, stream>>>(X, W1t, dinv, h1s, n);
    k_agg1<<<(n / 2 + 3) / 4, 256, 0, stream>>>(h1s, row_ptr, csr, dinv, b1, tbuf, n);
    k_gemm2<<<((size_t)n * 16 + 255) / 256, 256, 0, stream>>>(tbuf, W2, dinv, h2s, n);
    k_agg2<<<(n + 63) / 64, 256, 0, stream>>>(h2s, row_ptr, csr, dinv, b2, out, n);
}